// Round 7
// baseline (749.672 us; speedup 1.0000x reference)
//
#include <hip/hip_runtime.h>
#include <hip/hip_bf16.h>

#define NN 100000
#define NE 3200000
#define HID 256
#define SDIM 128
#define ADIM 64
#define BN_EPS 1e-5f

#define BSH 9                       // 512 nodes per bucket
#define NB 196                      // ceil(NN/512)
#define EPB 8192                    // edges per partition block
#define NAB 391                     // ceil(NE/EPB)

typedef __attribute__((ext_vector_type(8))) short short8;
typedef __attribute__((ext_vector_type(4))) float f32x4;

__device__ __forceinline__ void atomAdd(float* p, float v) { unsafeAtomicAdd(p, v); }
__device__ __forceinline__ float bf2f(ushort u) {
    union { unsigned i; float f; } c; c.i = ((unsigned)u) << 16; return c.f;
}
__device__ __forceinline__ ushort f2bf(float x) {
    __hip_bfloat16 h = __float2bfloat16(x);
    return *reinterpret_cast<ushort*>(&h);
}

// ---------------- A0: global bucket histograms (dst + src) ----------------
__global__ __launch_bounds__(1024)
void k_hist(const int* __restrict__ src, const int* __restrict__ dst,
            unsigned* __restrict__ gh_d, unsigned* __restrict__ gh_s, int E) {
    __shared__ unsigned hd[NB], hs[NB];
    int tid = threadIdx.x;
    if (tid < NB) { hd[tid] = 0; hs[tid] = 0; }
    __syncthreads();
    int base = blockIdx.x * EPB;
    int cnt = min(EPB, E - base);
    for (int i = tid; i < cnt; i += 1024) {
        atomicAdd(&hd[dst[base + i] >> BSH], 1u);
        atomicAdd(&hs[src[base + i] >> BSH], 1u);
    }
    __syncthreads();
    if (tid < NB) {
        if (hd[tid]) atomicAdd(&gh_d[tid * 16], hd[tid]);
        if (hs[tid]) atomicAdd(&gh_s[tid * 16], hs[tid]);
    }
}

// ---------------- scan bucket totals -> bases + cursors ----------------
__global__ __launch_bounds__(256)
void k_scan_b(const unsigned* __restrict__ gh_d, const unsigned* __restrict__ gh_s,
              unsigned* __restrict__ gcur_d, unsigned* __restrict__ gcur_s,
              unsigned* __restrict__ bbase_d, unsigned* __restrict__ bbase_s,
              int* __restrict__ row_ptr) {
    __shared__ unsigned v[256];
    int t = threadIdx.x;
    unsigned x = (t < NB) ? gh_d[t * 16] : 0;
    v[t] = x; __syncthreads();
    for (int off = 1; off < 256; off <<= 1) {
        unsigned a = (t >= off) ? v[t - off] : 0;
        __syncthreads(); v[t] += a; __syncthreads();
    }
    if (t < NB) { bbase_d[t] = v[t] - x; gcur_d[t * 16] = v[t] - x; }
    if (t == 255) { bbase_d[NB] = v[255]; row_ptr[NN] = (int)v[255]; }
    __syncthreads();
    unsigned y = (t < NB) ? gh_s[t * 16] : 0;
    v[t] = y; __syncthreads();
    for (int off = 1; off < 256; off <<= 1) {
        unsigned a = (t >= off) ? v[t - off] : 0;
        __syncthreads(); v[t] += a; __syncthreads();
    }
    if (t < NB) { bbase_s[t] = v[t] - y; gcur_s[t * 16] = v[t] - y; }
    if (t == 255) bbase_s[NB] = v[255];
}

// ---------------- A1: partition edges into buckets (LDS compaction) ----------------
__global__ __launch_bounds__(1024)
void k_part(const int* __restrict__ src, const int* __restrict__ dst,
            unsigned* __restrict__ gcur_d, unsigned* __restrict__ gcur_s,
            unsigned* __restrict__ outd, ushort* __restrict__ outs, int E) {
    __shared__ unsigned hd[NB], hs[NB], ld_[NB], ls_[NB], cd[NB], cs[NB], bd[NB], bs[NB];
    __shared__ unsigned sv[256];
    __shared__ unsigned stage_d[EPB];
    __shared__ ushort stage_s[EPB];
    __shared__ unsigned char sbd[EPB], sbs[EPB];
    const int tid = threadIdx.x;
    const int base = blockIdx.x * EPB;
    const int cnt = min(EPB, E - base);
    if (tid < NB) { hd[tid] = 0; hs[tid] = 0; }
    __syncthreads();

    int es[8], ed[8];
    #pragma unroll
    for (int i = 0; i < 8; ++i) {
        int g = tid + i * 1024;
        if (g < cnt) { es[i] = src[base + g]; ed[i] = dst[base + g]; }
        else { es[i] = -1; ed[i] = -1; }
    }
    #pragma unroll
    for (int i = 0; i < 8; ++i)
        if (ed[i] >= 0) {
            atomicAdd(&hd[ed[i] >> BSH], 1u);
            atomicAdd(&hs[es[i] >> BSH], 1u);
        }
    __syncthreads();

    {
        unsigned x = (tid < NB) ? hd[tid] : 0;
        if (tid < 256) sv[tid] = x;
        __syncthreads();
        for (int off = 1; off < 256; off <<= 1) {
            unsigned a = 0;
            if (tid < 256 && tid >= off) a = sv[tid - off];
            __syncthreads();
            if (tid < 256) sv[tid] += a;
            __syncthreads();
        }
        if (tid < NB) {
            ld_[tid] = sv[tid] - x; cd[tid] = sv[tid] - x;
            bd[tid] = atomicAdd(&gcur_d[tid * 16], hd[tid]);
        }
        __syncthreads();
        unsigned y = (tid < NB) ? hs[tid] : 0;
        if (tid < 256) sv[tid] = y;
        __syncthreads();
        for (int off = 1; off < 256; off <<= 1) {
            unsigned a = 0;
            if (tid < 256 && tid >= off) a = sv[tid - off];
            __syncthreads();
            if (tid < 256) sv[tid] += a;
            __syncthreads();
        }
        if (tid < NB) {
            ls_[tid] = sv[tid] - y; cs[tid] = sv[tid] - y;
            bs[tid] = atomicAdd(&gcur_s[tid * 16], hs[tid]);
        }
        __syncthreads();
    }

    #pragma unroll
    for (int i = 0; i < 8; ++i)
        if (ed[i] >= 0) {
            int b = ed[i] >> BSH;
            unsigned p = atomicAdd(&cd[b], 1u);
            stage_d[p] = ((unsigned)(ed[i] & ((1 << BSH) - 1)) << 17) | (unsigned)es[i];
            sbd[p] = (unsigned char)b;
            int b2 = es[i] >> BSH;
            unsigned p2 = atomicAdd(&cs[b2], 1u);
            stage_s[p2] = (ushort)(es[i] & ((1 << BSH) - 1));
            sbs[p2] = (unsigned char)b2;
        }
    __syncthreads();

    for (int i = tid; i < cnt; i += 1024) {
        unsigned b = sbd[i];
        outd[bd[b] + (unsigned)i - ld_[b]] = stage_d[i];
        unsigned b2 = sbs[i];
        outs[bs[b2] + (unsigned)i - ls_[b2]] = stage_s[i];
    }
}

// ---------------- B: per-bucket CSR finalize (direct global scatter, no LDS staging) ----------------
__global__ __launch_bounds__(1024)
void k_csr(const unsigned* __restrict__ outd, const unsigned* __restrict__ bbase_d,
           int* __restrict__ row_ptr, int* __restrict__ csr_src, float* __restrict__ dni) {
    __shared__ unsigned h[512], sc[512];
    const int tid = threadIdx.x, b = blockIdx.x;
    const unsigned beg = bbase_d[b], end = bbase_d[b + 1];
    const int cnt = (int)(end - beg);
    if (tid < 512) h[tid] = 0;
    __syncthreads();
    for (int i = tid; i < cnt; i += 1024) atomicAdd(&h[outd[beg + i] >> 17], 1u);
    __syncthreads();
    unsigned my = 0;
    if (tid < 512) { my = h[tid]; sc[tid] = my; }
    __syncthreads();
    for (int off = 1; off < 512; off <<= 1) {
        unsigned a = 0;
        if (tid < 512 && tid >= off) a = sc[tid - off];
        __syncthreads();
        if (tid < 512) sc[tid] += a;
        __syncthreads();
    }
    const int n0 = b << BSH;
    const int nb = min(512, NN - n0);
    unsigned excl = 0;
    if (tid < 512) excl = sc[tid] - my;
    __syncthreads();
    if (tid < 512) h[tid] = excl;
    if (tid < nb) {
        row_ptr[n0 + tid] = (int)(beg + excl);
        dni[n0 + tid] = rsqrtf(fmaxf((float)my, 1.0f));
    }
    __syncthreads();
    // scatter directly to global: per-bucket span ~64 KB stays L2-resident
    for (int i = tid; i < cnt; i += 1024) {
        unsigned p = outd[beg + i];
        unsigned pos = atomicAdd(&h[p >> 17], 1u);
        csr_src[beg + pos] = (int)(p & 0x1FFFFu);
    }
}

// ---------------- out-degrees -> dno, fused with feat prescale -> bf16 ----------------
__global__ __launch_bounds__(1024)
void k_degout_ps(const ushort* __restrict__ outs, const unsigned* __restrict__ bbase_s,
                 const float* __restrict__ feat, float* __restrict__ dno,
                 ushort* __restrict__ Xb) {
    __shared__ unsigned h[512];
    __shared__ float dnl[512];
    const int tid = threadIdx.x, b = blockIdx.x;
    const unsigned beg = bbase_s[b], end = bbase_s[b + 1];
    const int cnt = (int)(end - beg);
    if (tid < 512) h[tid] = 0;
    __syncthreads();
    for (int i = tid; i < cnt; i += 1024) atomicAdd(&h[outs[beg + i]], 1u);
    __syncthreads();
    const int n0 = b << BSH;
    const int nb = min(512, NN - n0);
    if (tid < nb) {
        float d = rsqrtf(fmaxf((float)h[tid], 1.0f));
        dno[n0 + tid] = d;
        dnl[tid] = d;
    }
    __syncthreads();
    // prescale feat rows n0..n0+nb-1 (32 float4 per row)
    const int total4 = nb * 32;
    for (int slot = tid; slot < total4; slot += 1024) {
        int r = slot >> 5, c4 = slot & 31;
        float s = dnl[r];
        float4 v = reinterpret_cast<const float4*>(feat)[(size_t)(n0 + r) * 32 + c4];
        ushort4 o;
        o.x = f2bf(v.x * s); o.y = f2bf(v.y * s);
        o.z = f2bf(v.z * s); o.w = f2bf(v.w * s);
        reinterpret_cast<ushort4*>(Xb)[(size_t)(n0 + r) * 32 + c4] = o;
    }
}

// ---------------- weight prep: Wt1[256][128], Wt2[256][256], Wh[80][256] bf16 ----------------
__global__ __launch_bounds__(256)
void k_wprep(const float* __restrict__ W1, const float* __restrict__ W2,
             const float* __restrict__ Wa, const float* __restrict__ Wv,
             ushort* __restrict__ Wt1, ushort* __restrict__ Wt2, ushort* __restrict__ Wh) {
    int idx = blockIdx.x * 256 + threadIdx.x;
    if (idx < HID * SDIM) {
        int n = idx / SDIM, k = idx - n * SDIM;
        Wt1[idx] = f2bf(W1[(size_t)k * HID + n]);
    } else if (idx < HID * SDIM + HID * HID) {
        int j = idx - HID * SDIM;
        int n = j / HID, k = j - n * HID;
        Wt2[j] = f2bf(W2[(size_t)k * HID + n]);
    } else if (idx < HID * SDIM + HID * HID + 80 * HID) {
        int j = idx - HID * SDIM - HID * HID;
        int n = j / HID, k = j - n * HID;
        float v = 0.f;
        if (n < ADIM) v = Wa[(size_t)k * ADIM + n];
        else if (n == ADIM) v = Wv[k];
        Wh[j] = f2bf(v);
    }
}

// ---------------- pull SpMM over bf16 rows ----------------
template <int F>
__global__ __launch_bounds__(256)
void k_spmm_bf16(const int* __restrict__ row_ptr, const int* __restrict__ csr_src,
                 const ushort* __restrict__ X, const float* __restrict__ dni,
                 ushort* __restrict__ Y, int N) {
    const int node = blockIdx.x * 4 + (threadIdx.x >> 6);
    if (node >= N) return;
    const int lane = threadIdx.x & 63;
    const int beg = row_ptr[node];
    const int end = row_ptr[node + 1];
    float acc[4] = {0.f, 0.f, 0.f, 0.f};

    if (F == 256) {
        const ushort* Xl = X + lane * 4;
        int e = beg;
        for (; e + 1 < end; e += 2) {
            int s0 = csr_src[e];
            int s1 = csr_src[e + 1];
            ushort4 v0 = *reinterpret_cast<const ushort4*>(Xl + (size_t)s0 * 256);
            ushort4 v1 = *reinterpret_cast<const ushort4*>(Xl + (size_t)s1 * 256);
            acc[0] += bf2f(v0.x) + bf2f(v1.x);
            acc[1] += bf2f(v0.y) + bf2f(v1.y);
            acc[2] += bf2f(v0.z) + bf2f(v1.z);
            acc[3] += bf2f(v0.w) + bf2f(v1.w);
        }
        if (e < end) {
            int s0 = csr_src[e];
            ushort4 v0 = *reinterpret_cast<const ushort4*>(Xl + (size_t)s0 * 256);
            acc[0] += bf2f(v0.x); acc[1] += bf2f(v0.y);
            acc[2] += bf2f(v0.z); acc[3] += bf2f(v0.w);
        }
        float wi = dni[node];
        ushort4 o;
        o.x = f2bf(acc[0] * wi); o.y = f2bf(acc[1] * wi);
        o.z = f2bf(acc[2] * wi); o.w = f2bf(acc[3] * wi);
        *reinterpret_cast<ushort4*>(Y + (size_t)node * 256 + lane * 4) = o;
    } else {
        const int half = lane >> 5;
        const int l = lane & 31;
        const ushort* Xl = X + l * 4;
        for (int e = beg + half; e < end; e += 2) {
            int s = csr_src[e];
            ushort4 v = *reinterpret_cast<const ushort4*>(Xl + (size_t)s * 128);
            acc[0] += bf2f(v.x); acc[1] += bf2f(v.y);
            acc[2] += bf2f(v.z); acc[3] += bf2f(v.w);
        }
        acc[0] += __shfl_xor(acc[0], 32);
        acc[1] += __shfl_xor(acc[1], 32);
        acc[2] += __shfl_xor(acc[2], 32);
        acc[3] += __shfl_xor(acc[3], 32);
        if (half == 0) {
            float wi = dni[node];
            ushort4 o;
            o.x = f2bf(acc[0] * wi); o.y = f2bf(acc[1] * wi);
            o.z = f2bf(acc[2] * wi); o.w = f2bf(acc[3] * wi);
            *reinterpret_cast<ushort4*>(Y + (size_t)node * 128 + l * 4) = o;
        }
    }
}

// ---------------- MFMA GEMM 128x256 tile + fused BN column stats ----------------
template <int K>
__global__ __launch_bounds__(256, 2)
void k_gemm_mfma(const ushort* __restrict__ A, const ushort* __restrict__ Wt,
                 const float* __restrict__ bias, ushort* __restrict__ outb,
                 float* __restrict__ stats, int M) {
    __shared__ ushort As[128][40];
    __shared__ ushort Bs[256][40];
    __shared__ float sred[4][2][128];
    const int tid = threadIdx.x;
    const int w = tid >> 6;
    const int lane = tid & 63;
    const int wr = (w >> 1) * 64;
    const int wc = (w & 1) * 128;
    const int row0 = blockIdx.x * 128;
    f32x4 acc[4][8] = {};

    const int frow = lane & 15;
    const int fk = (lane >> 4) * 8;

    for (int k0 = 0; k0 < K; k0 += 32) {
        #pragma unroll
        for (int h = 0; h < 2; ++h) {
            int slot = tid + 256 * h;
            int r = slot >> 2;
            int c = (slot & 3) * 8;
            int row = row0 + r;
            int4 v = make_int4(0, 0, 0, 0);
            if (row < M) v = *reinterpret_cast<const int4*>(A + (size_t)row * K + k0 + c);
            *reinterpret_cast<int4*>(&As[r][c]) = v;
        }
        #pragma unroll
        for (int h = 0; h < 4; ++h) {
            int slot = tid + 256 * h;
            int n = slot >> 2;
            int c = (slot & 3) * 8;
            int4 v = *reinterpret_cast<const int4*>(Wt + (size_t)n * K + k0 + c);
            *reinterpret_cast<int4*>(&Bs[n][c]) = v;
        }
        __syncthreads();

        short8 afr[4], bfr[8];
        #pragma unroll
        for (int mi = 0; mi < 4; ++mi)
            afr[mi] = *reinterpret_cast<const short8*>(&As[wr + mi * 16 + frow][fk]);
        #pragma unroll
        for (int ni = 0; ni < 8; ++ni)
            bfr[ni] = *reinterpret_cast<const short8*>(&Bs[wc + ni * 16 + frow][fk]);
        #pragma unroll
        for (int mi = 0; mi < 4; ++mi)
            #pragma unroll
            for (int ni = 0; ni < 8; ++ni)
                acc[mi][ni] = __builtin_amdgcn_mfma_f32_16x16x32_bf16(afr[mi], bfr[ni], acc[mi][ni], 0, 0, 0);
        __syncthreads();
    }

    const int ncol = lane & 15;
    const int rbase = (lane >> 4) * 4;
    #pragma unroll
    for (int ni = 0; ni < 8; ++ni) {
        int col = wc + ni * 16 + ncol;
        float b = bias[col];
        float s1 = 0.f, s2 = 0.f;
        #pragma unroll
        for (int mi = 0; mi < 4; ++mi) {
            #pragma unroll
            for (int q = 0; q < 4; ++q) {
                int row = row0 + wr + mi * 16 + rbase + q;
                if (row < M) {
                    float val = acc[mi][ni][q] + b;
                    outb[(size_t)row * HID + col] = f2bf(val);
                    s1 += val;
                    s2 += val * val;
                }
            }
        }
        s1 += __shfl_xor(s1, 16); s1 += __shfl_xor(s1, 32);
        s2 += __shfl_xor(s2, 16); s2 += __shfl_xor(s2, 32);
        if ((lane >> 4) == 0) {
            sred[w][0][ni * 16 + ncol] = s1;
            sred[w][1][ni * 16 + ncol] = s2;
        }
    }
    __syncthreads();
    {
        int c = tid;
        int half = c >> 7, cl = c & 127;
        float v0 = sred[half][0][cl] + sred[half + 2][0][cl];
        float v1 = sred[half][1][cl] + sred[half + 2][1][cl];
        atomAdd(&stats[c], v0);
        atomAdd(&stats[HID + c], v1);
    }
}

// ---------------- BN + ReLU + dno-prescale: Gb bf16 -> Xb bf16 ----------------
__global__ __launch_bounds__(256)
void k_bn_relu_ps(const ushort* __restrict__ Gb, const float* __restrict__ stats,
                  const float* __restrict__ gamma, const float* __restrict__ beta,
                  const float* __restrict__ dno, ushort* __restrict__ Y, int total8) {
    int idx = blockIdx.x * 256 + threadIdx.x;
    if (idx >= total8) return;
    int row = idx >> 5;
    int c0 = (idx & 31) * 8;
    short8 v = *reinterpret_cast<const short8*>(Gb + (size_t)idx * 8);
    float s = dno[row];
    float inv_n = 1.0f / (float)NN;
    short8 o;
    #pragma unroll
    for (int j = 0; j < 8; ++j) {
        int c = c0 + j;
        float mean = stats[c] * inv_n;
        float var = stats[HID + c] * inv_n - mean * mean;
        float sc = gamma[c] * rsqrtf(var + BN_EPS);
        float sh = beta[c] - mean * sc;
        float x = bf2f((ushort)v[j]);
        float y = fmaf(x, sc, sh);
        y = y > 0.f ? y : 0.f;
        o[j] = (short)f2bf(y * s);
    }
    *reinterpret_cast<short8*>(Y + (size_t)idx * 8) = o;
}

// ---------------- fused BN2 + ReLU + dueling Q head (MFMA) ----------------
__global__ __launch_bounds__(256)
void k_bn_qhead(const ushort* __restrict__ Gb, const float* __restrict__ stats,
                const float* __restrict__ gamma, const float* __restrict__ beta,
                const ushort* __restrict__ Wh, const float* __restrict__ ba,
                const float* __restrict__ bv, float* __restrict__ out, int M) {
    __shared__ ushort As[128][40];
    __shared__ ushort Bs[80][264];
    __shared__ float sc_s[HID], sh_s[HID];
    const int tid = threadIdx.x;
    const int w = tid >> 6;
    const int lane = tid & 63;
    const int row0 = blockIdx.x * 128;
    const int frow = lane & 15;
    const int fk8 = (lane >> 4) * 8;

    {
        float inv_n = 1.0f / (float)NN;
        float mean = stats[tid] * inv_n;
        float var = stats[HID + tid] * inv_n - mean * mean;
        float sc = gamma[tid] * rsqrtf(var + BN_EPS);
        sc_s[tid] = sc;
        sh_s[tid] = beta[tid] - mean * sc;
    }
    #pragma unroll
    for (int h = 0; h < 10; ++h) {
        int slot = tid + 256 * h;
        int n = slot >> 5;
        int c = (slot & 31) * 8;
        int4 v = *reinterpret_cast<const int4*>(Wh + (size_t)n * HID + c);
        *reinterpret_cast<int4*>(&Bs[n][c]) = v;
    }
    __syncthreads();

    f32x4 acc[2][5] = {};
    for (int k0 = 0; k0 < HID; k0 += 32) {
        #pragma unroll
        for (int h = 0; h < 2; ++h) {
            int slot = tid + 256 * h;
            int r = slot >> 2;
            int c = (slot & 3) * 8;
            int row = row0 + r;
            short8 o = {};
            if (row < M) {
                short8 v = *reinterpret_cast<const short8*>(Gb + (size_t)row * HID + k0 + c);
                #pragma unroll
                for (int j = 0; j < 8; ++j) {
                    int k = k0 + c + j;
                    float y = fmaf(bf2f((ushort)v[j]), sc_s[k], sh_s[k]);
                    o[j] = (short)f2bf(y > 0.f ? y : 0.f);
                }
            }
            *reinterpret_cast<short8*>(&As[r][c]) = o;
        }
        __syncthreads();
        short8 afr[2], bfr[5];
        #pragma unroll
        for (int mi = 0; mi < 2; ++mi)
            afr[mi] = *reinterpret_cast<const short8*>(&As[w * 32 + mi * 16 + frow][fk8]);
        #pragma unroll
        for (int ni = 0; ni < 5; ++ni)
            bfr[ni] = *reinterpret_cast<const short8*>(&Bs[ni * 16 + frow][k0 + fk8]);
        #pragma unroll
        for (int mi = 0; mi < 2; ++mi)
            #pragma unroll
            for (int ni = 0; ni < 5; ++ni)
                acc[mi][ni] = __builtin_amdgcn_mfma_f32_16x16x32_bf16(afr[mi], bfr[ni], acc[mi][ni], 0, 0, 0);
        __syncthreads();
    }

    const int ncol = lane & 15;
    const int gb = lane & 48;
    const float bv0 = bv[0];
    float ba_l[4];
    #pragma unroll
    for (int ni = 0; ni < 4; ++ni) ba_l[ni] = ba[ni * 16 + ncol];
    #pragma unroll
    for (int mi = 0; mi < 2; ++mi) {
        #pragma unroll
        for (int q = 0; q < 4; ++q) {
            int row = row0 + w * 32 + mi * 16 + (lane >> 4) * 4 + q;
            float adv[4];
            float s = 0.f;
            #pragma unroll
            for (int ni = 0; ni < 4; ++ni) {
                adv[ni] = acc[mi][ni][q] + ba_l[ni];
                s += adv[ni];
            }
            s += __shfl_xor(s, 1); s += __shfl_xor(s, 2);
            s += __shfl_xor(s, 4); s += __shfl_xor(s, 8);
            float mean = s * (1.0f / ADIM);
            float val = acc[mi][4][q] + bv0;
            val = __shfl(val, gb);
            if (row < M) {
                #pragma unroll
                for (int ni = 0; ni < 4; ++ni)
                    out[(size_t)row * ADIM + ni * 16 + ncol] = val + adv[ni] - mean;
            }
        }
    }
}

extern "C" void kernel_launch(void* const* d_in, const int* in_sizes, int n_in,
                              void* d_out, int out_size, void* d_ws, size_t ws_size,
                              hipStream_t stream) {
    const float* feat = (const float*)d_in[0];
    const int* src = (const int*)d_in[1];
    const int* dst = (const int*)d_in[2];
    const float* W1 = (const float*)d_in[3];
    const float* b1 = (const float*)d_in[4];
    const float* g1 = (const float*)d_in[5];
    const float* be1 = (const float*)d_in[6];
    const float* W2 = (const float*)d_in[7];
    const float* b2 = (const float*)d_in[8];
    const float* g2 = (const float*)d_in[9];
    const float* be2 = (const float*)d_in[10];
    const float* Wa = (const float*)d_in[11];
    const float* ba = (const float*)d_in[12];
    const float* Wv = (const float*)d_in[13];
    const float* bv = (const float*)d_in[14];
    float* out = (float*)d_out;

    char* w = (char*)d_ws;
    unsigned* gh_d   = (unsigned*)w;  w += (size_t)NB * 16 * 4;
    unsigned* gh_s   = (unsigned*)w;  w += (size_t)NB * 16 * 4;
    float* stats     = (float*)w;     w += 1024 * 4;
    unsigned* gcur_d = (unsigned*)w;  w += (size_t)NB * 16 * 4;
    unsigned* gcur_s = (unsigned*)w;  w += (size_t)NB * 16 * 4;
    unsigned* bbase_d= (unsigned*)w;  w += (NB + 4) * 4;
    unsigned* bbase_s= (unsigned*)w;  w += (NB + 4) * 4;
    float* dn_out    = (float*)w;     w += (size_t)NN * 4;
    float* dn_in     = (float*)w;     w += (size_t)NN * 4;
    int* row_ptr     = (int*)w;       w += (size_t)(NN + 4) * 4;
    unsigned* outd   = (unsigned*)w;  w += (size_t)NE * 4;
    ushort* outs     = (ushort*)w;    w += (size_t)NE * 2;
    int* csr_src     = (int*)w;       w += (size_t)NE * 4;
    ushort* Wt1      = (ushort*)w;    w += (size_t)HID * SDIM * 2;
    ushort* Wt2      = (ushort*)w;    w += (size_t)HID * HID * 2;
    ushort* Whb      = (ushort*)w;    w += (size_t)80 * HID * 2;
    ushort* Xb       = (ushort*)w;    w += (size_t)NN * HID * 2;
    ushort* Ab       = (ushort*)w;    w += (size_t)NN * HID * 2;
    ushort* Gb       = (ushort*)w;    w += (size_t)NN * HID * 2;

    // zero bucket histograms + stats (contiguous)
    hipMemsetAsync(gh_d, 0, (size_t)2 * NB * 16 * 4 + 1024 * 4, stream);

    // weight prep (independent of CSR)
    {
        int total = HID * SDIM + HID * HID + 80 * HID;
        k_wprep<<<(total + 255) / 256, 256, 0, stream>>>(W1, W2, Wa, Wv, Wt1, Wt2, Whb);
    }

    // CSR build via two-level counting sort
    k_hist<<<NAB, 1024, 0, stream>>>(src, dst, gh_d, gh_s, NE);
    k_scan_b<<<1, 256, 0, stream>>>(gh_d, gh_s, gcur_d, gcur_s, bbase_d, bbase_s, row_ptr);
    k_part<<<NAB, 1024, 0, stream>>>(src, dst, gcur_d, gcur_s, outd, outs, NE);
    k_csr<<<NB, 1024, 0, stream>>>(outd, bbase_d, row_ptr, csr_src, dn_in);
    k_degout_ps<<<NB, 1024, 0, stream>>>(outs, bbase_s, feat, dn_out, Xb);

    const int gblocks = (NN + 127) / 128;

    // layer 1
    {
        k_spmm_bf16<SDIM><<<(NN + 3) / 4, 256, 0, stream>>>(row_ptr, csr_src, Xb, dn_in, Ab, NN);
        k_gemm_mfma<SDIM><<<gblocks, 256, 0, stream>>>(Ab, Wt1, b1, Gb, stats, NN);
        int t8 = NN * (HID / 8);
        k_bn_relu_ps<<<(t8 + 255) / 256, 256, 0, stream>>>(Gb, stats, g1, be1, dn_out, Xb, t8);
    }

    // layer 2
    {
        k_spmm_bf16<HID><<<(NN + 3) / 4, 256, 0, stream>>>(row_ptr, csr_src, Xb, dn_in, Ab, NN);
        k_gemm_mfma<HID><<<gblocks, 256, 0, stream>>>(Ab, Wt2, b2, Gb, stats + 512, NN);
        k_bn_qhead<<<gblocks, 256, 0, stream>>>(Gb, stats + 512, g2, be2, Whb, ba, bv, out, NN);
    }
}

// Round 8
// 716.739 us; speedup vs baseline: 1.0459x; 1.0459x over previous
//
#include <hip/hip_runtime.h>
#include <hip/hip_bf16.h>

#define NN 100000
#define NE 3200000
#define HID 256
#define SDIM 128
#define ADIM 64
#define BN_EPS 1e-5f

#define BSH 9                       // 512 nodes per bucket
#define NB 196                      // ceil(NN/512)
#define EPB 16384                   // edges per partition block
#define NAB 196                     // ceil(NE/EPB)

typedef __attribute__((ext_vector_type(8))) short short8;
typedef __attribute__((ext_vector_type(4))) float f32x4;

__device__ __forceinline__ void atomAdd(float* p, float v) { unsafeAtomicAdd(p, v); }
__device__ __forceinline__ float bf2f(ushort u) {
    union { unsigned i; float f; } c; c.i = ((unsigned)u) << 16; return c.f;
}
__device__ __forceinline__ ushort f2bf(float x) {
    __hip_bfloat16 h = __float2bfloat16(x);
    return *reinterpret_cast<ushort*>(&h);
}

// wave-exclusive scan helper: returns exclusive prefix of t across 64 lanes
__device__ __forceinline__ unsigned wave_excl_scan(unsigned t, int lane) {
    unsigned p = t;
    #pragma unroll
    for (int d = 1; d < 64; d <<= 1) {
        unsigned q = __shfl_up(p, d);
        if (lane >= d) p += q;
    }
    return p - t;
}

// ---------------- A0: global bucket histograms (dst + src) ----------------
__global__ __launch_bounds__(1024)
void k_hist(const int* __restrict__ src, const int* __restrict__ dst,
            unsigned* __restrict__ gh_d, unsigned* __restrict__ gh_s, int E) {
    __shared__ unsigned hd[NB], hs[NB];
    int tid = threadIdx.x;
    if (tid < NB) { hd[tid] = 0; hs[tid] = 0; }
    __syncthreads();
    int base = blockIdx.x * EPB;
    int cnt = min(EPB, E - base);
    for (int i = tid; i < cnt; i += 1024) {
        atomicAdd(&hd[dst[base + i] >> BSH], 1u);
        atomicAdd(&hs[src[base + i] >> BSH], 1u);
    }
    __syncthreads();
    if (tid < NB) {
        if (hd[tid]) atomicAdd(&gh_d[tid * 16], hd[tid]);
        if (hs[tid]) atomicAdd(&gh_s[tid * 16], hs[tid]);
    }
}

// ---------------- scan bucket totals -> bases + cursors ----------------
__global__ __launch_bounds__(256)
void k_scan_b(const unsigned* __restrict__ gh_d, const unsigned* __restrict__ gh_s,
              unsigned* __restrict__ gcur_d, unsigned* __restrict__ gcur_s,
              unsigned* __restrict__ bbase_d, unsigned* __restrict__ bbase_s,
              int* __restrict__ row_ptr) {
    __shared__ unsigned v[256];
    int t = threadIdx.x;
    unsigned x = (t < NB) ? gh_d[t * 16] : 0;
    v[t] = x; __syncthreads();
    for (int off = 1; off < 256; off <<= 1) {
        unsigned a = (t >= off) ? v[t - off] : 0;
        __syncthreads(); v[t] += a; __syncthreads();
    }
    if (t < NB) { bbase_d[t] = v[t] - x; gcur_d[t * 16] = v[t] - x; }
    if (t == 255) { bbase_d[NB] = v[255]; row_ptr[NN] = (int)v[255]; }
    __syncthreads();
    unsigned y = (t < NB) ? gh_s[t * 16] : 0;
    v[t] = y; __syncthreads();
    for (int off = 1; off < 256; off <<= 1) {
        unsigned a = (t >= off) ? v[t - off] : 0;
        __syncthreads(); v[t] += a; __syncthreads();
    }
    if (t < NB) { bbase_s[t] = v[t] - y; gcur_s[t * 16] = v[t] - y; }
    if (t == 255) bbase_s[NB] = v[255];
}

// ---------------- A1: partition edges into buckets (LDS compaction, wave scans) ----------------
__global__ __launch_bounds__(1024)
void k_part(const int* __restrict__ src, const int* __restrict__ dst,
            unsigned* __restrict__ gcur_d, unsigned* __restrict__ gcur_s,
            unsigned* __restrict__ outd, ushort* __restrict__ outs, int E) {
    __shared__ unsigned hd[NB], hs[NB], ld_[NB], ls_[NB], cd[NB], cs[NB], bd[NB], bs[NB];
    __shared__ unsigned stage_d[EPB];
    __shared__ ushort stage_s[EPB];
    __shared__ unsigned char sbd[EPB], sbs[EPB];
    const int tid = threadIdx.x;
    const int base = blockIdx.x * EPB;
    const int cnt = min(EPB, E - base);
    if (tid < NB) { hd[tid] = 0; hs[tid] = 0; }
    __syncthreads();

    int es[16], ed[16];
    #pragma unroll
    for (int i = 0; i < 16; ++i) {
        int g = tid + i * 1024;
        if (g < cnt) { es[i] = src[base + g]; ed[i] = dst[base + g]; }
        else { es[i] = -1; ed[i] = -1; }
    }
    #pragma unroll
    for (int i = 0; i < 16; ++i)
        if (ed[i] >= 0) {
            atomicAdd(&hd[ed[i] >> BSH], 1u);
            atomicAdd(&hs[es[i] >> BSH], 1u);
        }
    __syncthreads();

    // 4 waves do independent work: scans (barrier-free) + global cursor reservation
    {
        const int wv = tid >> 6, lane = tid & 63;
        if (wv == 0) {
            unsigned v[4]; unsigned t = 0;
            #pragma unroll
            for (int j = 0; j < 4; ++j) {
                int i = lane * 4 + j;
                v[j] = (i < NB) ? hd[i] : 0; t += v[j];
            }
            unsigned excl = wave_excl_scan(t, lane);
            #pragma unroll
            for (int j = 0; j < 4; ++j) {
                int i = lane * 4 + j;
                if (i < NB) { ld_[i] = excl; cd[i] = excl; }
                excl += v[j];
            }
        } else if (wv == 1) {
            unsigned v[4]; unsigned t = 0;
            #pragma unroll
            for (int j = 0; j < 4; ++j) {
                int i = lane * 4 + j;
                v[j] = (i < NB) ? hs[i] : 0; t += v[j];
            }
            unsigned excl = wave_excl_scan(t, lane);
            #pragma unroll
            for (int j = 0; j < 4; ++j) {
                int i = lane * 4 + j;
                if (i < NB) { ls_[i] = excl; cs[i] = excl; }
                excl += v[j];
            }
        } else if (wv == 2) {
            for (int i = lane; i < NB; i += 64) bd[i] = atomicAdd(&gcur_d[i * 16], hd[i]);
        } else if (wv == 3) {
            for (int i = lane; i < NB; i += 64) bs[i] = atomicAdd(&gcur_s[i * 16], hs[i]);
        }
    }
    __syncthreads();

    #pragma unroll
    for (int i = 0; i < 16; ++i)
        if (ed[i] >= 0) {
            int b = ed[i] >> BSH;
            unsigned p = atomicAdd(&cd[b], 1u);
            stage_d[p] = ((unsigned)(ed[i] & ((1 << BSH) - 1)) << 17) | (unsigned)es[i];
            sbd[p] = (unsigned char)b;
            int b2 = es[i] >> BSH;
            unsigned p2 = atomicAdd(&cs[b2], 1u);
            stage_s[p2] = (ushort)(es[i] & ((1 << BSH) - 1));
            sbs[p2] = (unsigned char)b2;
        }
    __syncthreads();

    for (int i = tid; i < cnt; i += 1024) {
        unsigned b = sbd[i];
        outd[bd[b] + (unsigned)i - ld_[b]] = stage_d[i];
        unsigned b2 = sbs[i];
        outs[bs[b2] + (unsigned)i - ls_[b2]] = stage_s[i];
    }
}

// ---------------- B: per-bucket CSR finalize (wave scan, direct global scatter) ----------------
__global__ __launch_bounds__(1024)
void k_csr(const unsigned* __restrict__ outd, const unsigned* __restrict__ bbase_d,
           int* __restrict__ row_ptr, int* __restrict__ csr_src, float* __restrict__ dni) {
    __shared__ unsigned h[512], sc[512];
    const int tid = threadIdx.x, b = blockIdx.x;
    const unsigned beg = bbase_d[b], end = bbase_d[b + 1];
    const int cnt = (int)(end - beg);
    if (tid < 512) h[tid] = 0;
    __syncthreads();
    for (int i = tid; i < cnt; i += 1024) atomicAdd(&h[outd[beg + i] >> 17], 1u);
    __syncthreads();
    if (tid < 64) {
        const int lane = tid;
        unsigned v[8]; unsigned t = 0;
        #pragma unroll
        for (int j = 0; j < 8; ++j) { v[j] = h[lane * 8 + j]; t += v[j]; }
        unsigned excl = wave_excl_scan(t, lane);
        #pragma unroll
        for (int j = 0; j < 8; ++j) { sc[lane * 8 + j] = excl; excl += v[j]; }
    }
    __syncthreads();
    const int n0 = b << BSH;
    const int nb = min(512, NN - n0);
    if (tid < nb) {
        row_ptr[n0 + tid] = (int)(beg + sc[tid]);
        dni[n0 + tid] = rsqrtf(fmaxf((float)h[tid], 1.0f));
    }
    __syncthreads();
    // scatter directly to global using sc as cursor (bucket span ~64 KB, L2-resident)
    for (int i = tid; i < cnt; i += 1024) {
        unsigned p = outd[beg + i];
        unsigned pos = atomicAdd(&sc[p >> 17], 1u);
        csr_src[beg + pos] = (int)(p & 0x1FFFFu);
    }
}

// ---------------- out-degrees -> dno, fused with feat prescale -> bf16 ----------------
__global__ __launch_bounds__(1024)
void k_degout_ps(const ushort* __restrict__ outs, const unsigned* __restrict__ bbase_s,
                 const float* __restrict__ feat, float* __restrict__ dno,
                 ushort* __restrict__ Xb) {
    __shared__ unsigned h[512];
    __shared__ float dnl[512];
    const int tid = threadIdx.x, b = blockIdx.x;
    const unsigned beg = bbase_s[b], end = bbase_s[b + 1];
    const int cnt = (int)(end - beg);
    if (tid < 512) h[tid] = 0;
    __syncthreads();
    for (int i = tid; i < cnt; i += 1024) atomicAdd(&h[outs[beg + i]], 1u);
    __syncthreads();
    const int n0 = b << BSH;
    const int nb = min(512, NN - n0);
    if (tid < nb) {
        float d = rsqrtf(fmaxf((float)h[tid], 1.0f));
        dno[n0 + tid] = d;
        dnl[tid] = d;
    }
    __syncthreads();
    const int total4 = nb * 32;
    for (int slot = tid; slot < total4; slot += 1024) {
        int r = slot >> 5, c4 = slot & 31;
        float s = dnl[r];
        float4 v = reinterpret_cast<const float4*>(feat)[(size_t)(n0 + r) * 32 + c4];
        ushort4 o;
        o.x = f2bf(v.x * s); o.y = f2bf(v.y * s);
        o.z = f2bf(v.z * s); o.w = f2bf(v.w * s);
        reinterpret_cast<ushort4*>(Xb)[(size_t)(n0 + r) * 32 + c4] = o;
    }
}

// ---------------- weight prep: Wt1[256][128], Wt2[256][256], Wh[80][256] bf16 ----------------
__global__ __launch_bounds__(256)
void k_wprep(const float* __restrict__ W1, const float* __restrict__ W2,
             const float* __restrict__ Wa, const float* __restrict__ Wv,
             ushort* __restrict__ Wt1, ushort* __restrict__ Wt2, ushort* __restrict__ Wh) {
    int idx = blockIdx.x * 256 + threadIdx.x;
    if (idx < HID * SDIM) {
        int n = idx / SDIM, k = idx - n * SDIM;
        Wt1[idx] = f2bf(W1[(size_t)k * HID + n]);
    } else if (idx < HID * SDIM + HID * HID) {
        int j = idx - HID * SDIM;
        int n = j / HID, k = j - n * HID;
        Wt2[j] = f2bf(W2[(size_t)k * HID + n]);
    } else if (idx < HID * SDIM + HID * HID + 80 * HID) {
        int j = idx - HID * SDIM - HID * HID;
        int n = j / HID, k = j - n * HID;
        float v = 0.f;
        if (n < ADIM) v = Wa[(size_t)k * ADIM + n];
        else if (n == ADIM) v = Wv[k];
        Wh[j] = f2bf(v);
    }
}

// ---------------- pull SpMM over bf16 rows (layer 1, F=128) ----------------
__global__ __launch_bounds__(256)
void k_spmm_l1(const int* __restrict__ row_ptr, const int* __restrict__ csr_src,
               const ushort* __restrict__ X, const float* __restrict__ dni,
               ushort* __restrict__ Y, int N) {
    const int node = blockIdx.x * 4 + (threadIdx.x >> 6);
    if (node >= N) return;
    const int lane = threadIdx.x & 63;
    const int beg = row_ptr[node];
    const int end = row_ptr[node + 1];
    float acc[4] = {0.f, 0.f, 0.f, 0.f};
    const int half = lane >> 5;
    const int l = lane & 31;
    const ushort* Xl = X + l * 4;
    for (int e = beg + half; e < end; e += 2) {
        int s = csr_src[e];
        ushort4 v = *reinterpret_cast<const ushort4*>(Xl + (size_t)s * 128);
        acc[0] += bf2f(v.x); acc[1] += bf2f(v.y);
        acc[2] += bf2f(v.z); acc[3] += bf2f(v.w);
    }
    acc[0] += __shfl_xor(acc[0], 32);
    acc[1] += __shfl_xor(acc[1], 32);
    acc[2] += __shfl_xor(acc[2], 32);
    acc[3] += __shfl_xor(acc[3], 32);
    if (half == 0) {
        float wi = dni[node];
        ushort4 o;
        o.x = f2bf(acc[0] * wi); o.y = f2bf(acc[1] * wi);
        o.z = f2bf(acc[2] * wi); o.w = f2bf(acc[3] * wi);
        *reinterpret_cast<ushort4*>(Y + (size_t)node * 128 + l * 4) = o;
    }
}

// ---------------- fused BN1+ReLU+dno-prescale + pull SpMM (layer 2, F=256) ----------------
// Ab[n,:] = bf16( dni[n] * sum_e dno[src_e] * relu(BN(Gb[src_e,:])) )
__global__ __launch_bounds__(256)
void k_spmm_bn(const int* __restrict__ row_ptr, const int* __restrict__ csr_src,
               const ushort* __restrict__ Gb, const float* __restrict__ stats,
               const float* __restrict__ gamma, const float* __restrict__ beta,
               const float* __restrict__ dno, const float* __restrict__ dni,
               ushort* __restrict__ Y, int N) {
    __shared__ float sc_s[HID], sh_s[HID];
    {
        int c = threadIdx.x;
        float inv_n = 1.0f / (float)NN;
        float mean = stats[c] * inv_n;
        float var = stats[HID + c] * inv_n - mean * mean;
        float sc = gamma[c] * rsqrtf(var + BN_EPS);
        sc_s[c] = sc;
        sh_s[c] = beta[c] - mean * sc;
    }
    __syncthreads();
    const int node = blockIdx.x * 4 + (threadIdx.x >> 6);
    if (node >= N) return;
    const int lane = threadIdx.x & 63;
    const int c0 = lane * 4;
    float sc[4], sh[4];
    #pragma unroll
    for (int j = 0; j < 4; ++j) { sc[j] = sc_s[c0 + j]; sh[j] = sh_s[c0 + j]; }
    const int beg = row_ptr[node];
    const int end = row_ptr[node + 1];
    float acc[4] = {0.f, 0.f, 0.f, 0.f};
    const ushort* Gl = Gb + c0;
    int e = beg;
    for (; e + 1 < end; e += 2) {
        int s0 = csr_src[e];
        int s1 = csr_src[e + 1];
        float w0 = dno[s0];
        float w1 = dno[s1];
        ushort4 v0 = *reinterpret_cast<const ushort4*>(Gl + (size_t)s0 * 256);
        ushort4 v1 = *reinterpret_cast<const ushort4*>(Gl + (size_t)s1 * 256);
        const ushort* p0 = &v0.x;
        const ushort* p1 = &v1.x;
        #pragma unroll
        for (int j = 0; j < 4; ++j) {
            float y0 = fmaf(bf2f(p0[j]), sc[j], sh[j]);
            y0 = y0 > 0.f ? y0 : 0.f;
            acc[j] = fmaf(y0, w0, acc[j]);
            float y1 = fmaf(bf2f(p1[j]), sc[j], sh[j]);
            y1 = y1 > 0.f ? y1 : 0.f;
            acc[j] = fmaf(y1, w1, acc[j]);
        }
    }
    if (e < end) {
        int s0 = csr_src[e];
        float w0 = dno[s0];
        ushort4 v0 = *reinterpret_cast<const ushort4*>(Gl + (size_t)s0 * 256);
        const ushort* p0 = &v0.x;
        #pragma unroll
        for (int j = 0; j < 4; ++j) {
            float y0 = fmaf(bf2f(p0[j]), sc[j], sh[j]);
            y0 = y0 > 0.f ? y0 : 0.f;
            acc[j] = fmaf(y0, w0, acc[j]);
        }
    }
    float wi = dni[node];
    ushort4 o;
    o.x = f2bf(acc[0] * wi); o.y = f2bf(acc[1] * wi);
    o.z = f2bf(acc[2] * wi); o.w = f2bf(acc[3] * wi);
    *reinterpret_cast<ushort4*>(Y + (size_t)node * 256 + c0) = o;
}

// ---------------- MFMA GEMM 128x256 tile + fused BN column stats ----------------
template <int K>
__global__ __launch_bounds__(256, 2)
void k_gemm_mfma(const ushort* __restrict__ A, const ushort* __restrict__ Wt,
                 const float* __restrict__ bias, ushort* __restrict__ outb,
                 float* __restrict__ stats, int M) {
    __shared__ ushort As[128][40];
    __shared__ ushort Bs[256][40];
    __shared__ float sred[4][2][128];
    const int tid = threadIdx.x;
    const int w = tid >> 6;
    const int lane = tid & 63;
    const int wr = (w >> 1) * 64;
    const int wc = (w & 1) * 128;
    const int row0 = blockIdx.x * 128;
    f32x4 acc[4][8] = {};

    const int frow = lane & 15;
    const int fk = (lane >> 4) * 8;

    for (int k0 = 0; k0 < K; k0 += 32) {
        #pragma unroll
        for (int h = 0; h < 2; ++h) {
            int slot = tid + 256 * h;
            int r = slot >> 2;
            int c = (slot & 3) * 8;
            int row = row0 + r;
            int4 v = make_int4(0, 0, 0, 0);
            if (row < M) v = *reinterpret_cast<const int4*>(A + (size_t)row * K + k0 + c);
            *reinterpret_cast<int4*>(&As[r][c]) = v;
        }
        #pragma unroll
        for (int h = 0; h < 4; ++h) {
            int slot = tid + 256 * h;
            int n = slot >> 2;
            int c = (slot & 3) * 8;
            int4 v = *reinterpret_cast<const int4*>(Wt + (size_t)n * K + k0 + c);
            *reinterpret_cast<int4*>(&Bs[n][c]) = v;
        }
        __syncthreads();

        short8 afr[4], bfr[8];
        #pragma unroll
        for (int mi = 0; mi < 4; ++mi)
            afr[mi] = *reinterpret_cast<const short8*>(&As[wr + mi * 16 + frow][fk]);
        #pragma unroll
        for (int ni = 0; ni < 8; ++ni)
            bfr[ni] = *reinterpret_cast<const short8*>(&Bs[wc + ni * 16 + frow][fk]);
        #pragma unroll
        for (int mi = 0; mi < 4; ++mi)
            #pragma unroll
            for (int ni = 0; ni < 8; ++ni)
                acc[mi][ni] = __builtin_amdgcn_mfma_f32_16x16x32_bf16(afr[mi], bfr[ni], acc[mi][ni], 0, 0, 0);
        __syncthreads();
    }

    const int ncol = lane & 15;
    const int rbase = (lane >> 4) * 4;
    #pragma unroll
    for (int ni = 0; ni < 8; ++ni) {
        int col = wc + ni * 16 + ncol;
        float b = bias[col];
        float s1 = 0.f, s2 = 0.f;
        #pragma unroll
        for (int mi = 0; mi < 4; ++mi) {
            #pragma unroll
            for (int q = 0; q < 4; ++q) {
                int row = row0 + wr + mi * 16 + rbase + q;
                if (row < M) {
                    float val = acc[mi][ni][q] + b;
                    outb[(size_t)row * HID + col] = f2bf(val);
                    s1 += val;
                    s2 += val * val;
                }
            }
        }
        s1 += __shfl_xor(s1, 16); s1 += __shfl_xor(s1, 32);
        s2 += __shfl_xor(s2, 16); s2 += __shfl_xor(s2, 32);
        if ((lane >> 4) == 0) {
            sred[w][0][ni * 16 + ncol] = s1;
            sred[w][1][ni * 16 + ncol] = s2;
        }
    }
    __syncthreads();
    {
        int c = tid;
        int half = c >> 7, cl = c & 127;
        float v0 = sred[half][0][cl] + sred[half + 2][0][cl];
        float v1 = sred[half][1][cl] + sred[half + 2][1][cl];
        atomAdd(&stats[c], v0);
        atomAdd(&stats[HID + c], v1);
    }
}

// ---------------- fused BN2 + ReLU + dueling Q head (MFMA) ----------------
__global__ __launch_bounds__(256)
void k_bn_qhead(const ushort* __restrict__ Gb, const float* __restrict__ stats,
                const float* __restrict__ gamma, const float* __restrict__ beta,
                const ushort* __restrict__ Wh, const float* __restrict__ ba,
                const float* __restrict__ bv, float* __restrict__ out, int M) {
    __shared__ ushort As[128][40];
    __shared__ ushort Bs[80][264];
    __shared__ float sc_s[HID], sh_s[HID];
    const int tid = threadIdx.x;
    const int w = tid >> 6;
    const int lane = tid & 63;
    const int row0 = blockIdx.x * 128;
    const int frow = lane & 15;
    const int fk8 = (lane >> 4) * 8;

    {
        float inv_n = 1.0f / (float)NN;
        float mean = stats[tid] * inv_n;
        float var = stats[HID + tid] * inv_n - mean * mean;
        float sc = gamma[tid] * rsqrtf(var + BN_EPS);
        sc_s[tid] = sc;
        sh_s[tid] = beta[tid] - mean * sc;
    }
    #pragma unroll
    for (int h = 0; h < 10; ++h) {
        int slot = tid + 256 * h;
        int n = slot >> 5;
        int c = (slot & 31) * 8;
        int4 v = *reinterpret_cast<const int4*>(Wh + (size_t)n * HID + c);
        *reinterpret_cast<int4*>(&Bs[n][c]) = v;
    }
    __syncthreads();

    f32x4 acc[2][5] = {};
    for (int k0 = 0; k0 < HID; k0 += 32) {
        #pragma unroll
        for (int h = 0; h < 2; ++h) {
            int slot = tid + 256 * h;
            int r = slot >> 2;
            int c = (slot & 3) * 8;
            int row = row0 + r;
            short8 o = {};
            if (row < M) {
                short8 v = *reinterpret_cast<const short8*>(Gb + (size_t)row * HID + k0 + c);
                #pragma unroll
                for (int j = 0; j < 8; ++j) {
                    int k = k0 + c + j;
                    float y = fmaf(bf2f((ushort)v[j]), sc_s[k], sh_s[k]);
                    o[j] = (short)f2bf(y > 0.f ? y : 0.f);
                }
            }
            *reinterpret_cast<short8*>(&As[r][c]) = o;
        }
        __syncthreads();
        short8 afr[2], bfr[5];
        #pragma unroll
        for (int mi = 0; mi < 2; ++mi)
            afr[mi] = *reinterpret_cast<const short8*>(&As[w * 32 + mi * 16 + frow][fk8]);
        #pragma unroll
        for (int ni = 0; ni < 5; ++ni)
            bfr[ni] = *reinterpret_cast<const short8*>(&Bs[ni * 16 + frow][k0 + fk8]);
        #pragma unroll
        for (int mi = 0; mi < 2; ++mi)
            #pragma unroll
            for (int ni = 0; ni < 5; ++ni)
                acc[mi][ni] = __builtin_amdgcn_mfma_f32_16x16x32_bf16(afr[mi], bfr[ni], acc[mi][ni], 0, 0, 0);
        __syncthreads();
    }

    const int ncol = lane & 15;
    const int gb = lane & 48;
    const float bv0 = bv[0];
    float ba_l[4];
    #pragma unroll
    for (int ni = 0; ni < 4; ++ni) ba_l[ni] = ba[ni * 16 + ncol];
    #pragma unroll
    for (int mi = 0; mi < 2; ++mi) {
        #pragma unroll
        for (int q = 0; q < 4; ++q) {
            int row = row0 + w * 32 + mi * 16 + (lane >> 4) * 4 + q;
            float adv[4];
            float s = 0.f;
            #pragma unroll
            for (int ni = 0; ni < 4; ++ni) {
                adv[ni] = acc[mi][ni][q] + ba_l[ni];
                s += adv[ni];
            }
            s += __shfl_xor(s, 1); s += __shfl_xor(s, 2);
            s += __shfl_xor(s, 4); s += __shfl_xor(s, 8);
            float mean = s * (1.0f / ADIM);
            float val = acc[mi][4][q] + bv0;
            val = __shfl(val, gb);
            if (row < M) {
                #pragma unroll
                for (int ni = 0; ni < 4; ++ni)
                    out[(size_t)row * ADIM + ni * 16 + ncol] = val + adv[ni] - mean;
            }
        }
    }
}

extern "C" void kernel_launch(void* const* d_in, const int* in_sizes, int n_in,
                              void* d_out, int out_size, void* d_ws, size_t ws_size,
                              hipStream_t stream) {
    const float* feat = (const float*)d_in[0];
    const int* src = (const int*)d_in[1];
    const int* dst = (const int*)d_in[2];
    const float* W1 = (const float*)d_in[3];
    const float* b1 = (const float*)d_in[4];
    const float* g1 = (const float*)d_in[5];
    const float* be1 = (const float*)d_in[6];
    const float* W2 = (const float*)d_in[7];
    const float* b2 = (const float*)d_in[8];
    const float* g2 = (const float*)d_in[9];
    const float* be2 = (const float*)d_in[10];
    const float* Wa = (const float*)d_in[11];
    const float* ba = (const float*)d_in[12];
    const float* Wv = (const float*)d_in[13];
    const float* bv = (const float*)d_in[14];
    float* out = (float*)d_out;

    char* w = (char*)d_ws;
    unsigned* gh_d   = (unsigned*)w;  w += (size_t)NB * 16 * 4;
    unsigned* gh_s   = (unsigned*)w;  w += (size_t)NB * 16 * 4;
    float* stats     = (float*)w;     w += 1024 * 4;
    unsigned* gcur_d = (unsigned*)w;  w += (size_t)NB * 16 * 4;
    unsigned* gcur_s = (unsigned*)w;  w += (size_t)NB * 16 * 4;
    unsigned* bbase_d= (unsigned*)w;  w += (NB + 4) * 4;
    unsigned* bbase_s= (unsigned*)w;  w += (NB + 4) * 4;
    float* dn_out    = (float*)w;     w += (size_t)NN * 4;
    float* dn_in     = (float*)w;     w += (size_t)NN * 4;
    int* row_ptr     = (int*)w;       w += (size_t)(NN + 4) * 4;
    unsigned* outd   = (unsigned*)w;  w += (size_t)NE * 4;
    ushort* outs     = (ushort*)w;    w += (size_t)NE * 2;
    int* csr_src     = (int*)w;       w += (size_t)NE * 4;
    ushort* Wt1      = (ushort*)w;    w += (size_t)HID * SDIM * 2;
    ushort* Wt2      = (ushort*)w;    w += (size_t)HID * HID * 2;
    ushort* Whb      = (ushort*)w;    w += (size_t)80 * HID * 2;
    ushort* Xb       = (ushort*)w;    w += (size_t)NN * SDIM * 2;
    ushort* Ab       = (ushort*)w;    w += (size_t)NN * HID * 2;
    ushort* Gb       = (ushort*)w;    w += (size_t)NN * HID * 2;

    // zero bucket histograms + stats (contiguous)
    hipMemsetAsync(gh_d, 0, (size_t)2 * NB * 16 * 4 + 1024 * 4, stream);

    // weight prep (independent of CSR)
    {
        int total = HID * SDIM + HID * HID + 80 * HID;
        k_wprep<<<(total + 255) / 256, 256, 0, stream>>>(W1, W2, Wa, Wv, Wt1, Wt2, Whb);
    }

    // CSR build via two-level counting sort
    k_hist<<<NAB, 1024, 0, stream>>>(src, dst, gh_d, gh_s, NE);
    k_scan_b<<<1, 256, 0, stream>>>(gh_d, gh_s, gcur_d, gcur_s, bbase_d, bbase_s, row_ptr);
    k_part<<<NAB, 1024, 0, stream>>>(src, dst, gcur_d, gcur_s, outd, outs, NE);
    k_csr<<<NB, 1024, 0, stream>>>(outd, bbase_d, row_ptr, csr_src, dn_in);
    k_degout_ps<<<NB, 1024, 0, stream>>>(outs, bbase_s, feat, dn_out, Xb);

    const int gblocks = (NN + 127) / 128;

    // layer 1: spmm(feat_ps) -> gemm1 (+stats)
    k_spmm_l1<<<(NN + 3) / 4, 256, 0, stream>>>(row_ptr, csr_src, Xb, dn_in, Ab, NN);
    k_gemm_mfma<SDIM><<<gblocks, 256, 0, stream>>>(Ab, Wt1, b1, Gb, stats, NN);

    // layer 2: fused BN1+ReLU+prescale+spmm -> gemm2 (+stats) -> BN2+head
    k_spmm_bn<<<(NN + 3) / 4, 256, 0, stream>>>(row_ptr, csr_src, Gb, stats, g1, be1,
                                                dn_out, dn_in, Ab, NN);
    k_gemm_mfma<HID><<<gblocks, 256, 0, stream>>>(Ab, Wt2, b2, Gb, stats + 512, NN);
    k_bn_qhead<<<gblocks, 256, 0, stream>>>(Gb, stats + 512, g2, be2, Whb, ba, bv, out, NN);
}

// Round 9
// 701.116 us; speedup vs baseline: 1.0693x; 1.0223x over previous
//
#include <hip/hip_runtime.h>
#include <hip/hip_bf16.h>

#define NN 100000
#define NE 3200000
#define HID 256
#define SDIM 128
#define ADIM 64
#define BN_EPS 1e-5f

#define BSH 9                       // 512 nodes per bucket
#define NB 196                      // ceil(NN/512)
#define EPB 16384                   // edges per partition block
#define NAB 196                     // ceil(NE/EPB)
#define CAP 20480                   // fixed per-bucket capacity (mean 16384, sigma ~128)

typedef __attribute__((ext_vector_type(8))) short short8;
typedef __attribute__((ext_vector_type(4))) float f32x4;

__device__ __forceinline__ void atomAdd(float* p, float v) { unsafeAtomicAdd(p, v); }
__device__ __forceinline__ float bf2f(ushort u) {
    union { unsigned i; float f; } c; c.i = ((unsigned)u) << 16; return c.f;
}
__device__ __forceinline__ ushort f2bf(float x) {
    __hip_bfloat16 h = __float2bfloat16(x);
    return *reinterpret_cast<ushort*>(&h);
}

// wave-exclusive scan helper
__device__ __forceinline__ unsigned wave_excl_scan(unsigned t, int lane) {
    unsigned p = t;
    #pragma unroll
    for (int d = 1; d < 64; d <<= 1) {
        unsigned q = __shfl_up(p, d);
        if (lane >= d) p += q;
    }
    return p - t;
}

// ---------------- init: bucket cursors + stats ----------------
__global__ __launch_bounds__(256)
void k_init(unsigned* __restrict__ gcur_d, unsigned* __restrict__ gcur_s,
            float* __restrict__ stats) {
    int t = threadIdx.x;
    if (t < NB) {
        gcur_d[t * 16] = (unsigned)(t * CAP);
        gcur_s[t * 16] = (unsigned)(t * CAP);
    }
    #pragma unroll
    for (int j = 0; j < 4; ++j) stats[t + 256 * j] = 0.f;
}

// ---------------- weight prep: Wt1[256][128], Wt2[256][256], Wh[80][256] bf16 ----------------
__global__ __launch_bounds__(256)
void k_wprep(const float* __restrict__ W1, const float* __restrict__ W2,
             const float* __restrict__ Wa, const float* __restrict__ Wv,
             ushort* __restrict__ Wt1, ushort* __restrict__ Wt2, ushort* __restrict__ Wh) {
    int idx = blockIdx.x * 256 + threadIdx.x;
    if (idx < HID * SDIM) {
        int n = idx / SDIM, k = idx - n * SDIM;
        Wt1[idx] = f2bf(W1[(size_t)k * HID + n]);
    } else if (idx < HID * SDIM + HID * HID) {
        int j = idx - HID * SDIM;
        int n = j / HID, k = j - n * HID;
        Wt2[j] = f2bf(W2[(size_t)k * HID + n]);
    } else if (idx < HID * SDIM + HID * HID + 80 * HID) {
        int j = idx - HID * SDIM - HID * HID;
        int n = j / HID, k = j - n * HID;
        float v = 0.f;
        if (n < ADIM) v = Wa[(size_t)k * ADIM + n];
        else if (n == ADIM) v = Wv[k];
        Wh[j] = f2bf(v);
    }
}

// ---------------- A: partition edges into fixed-capacity buckets (single pass) ----------------
__global__ __launch_bounds__(1024)
void k_part(const int* __restrict__ src, const int* __restrict__ dst,
            unsigned* __restrict__ gcur_d, unsigned* __restrict__ gcur_s,
            unsigned* __restrict__ outd, ushort* __restrict__ outs, int E) {
    __shared__ unsigned hd[NB], hs[NB], ld_[NB], ls_[NB], cd[NB], cs[NB], bd[NB], bs[NB];
    __shared__ unsigned stage_d[EPB];
    __shared__ ushort stage_s[EPB];
    __shared__ unsigned char sbd[EPB], sbs[EPB];
    const int tid = threadIdx.x;
    const int base = blockIdx.x * EPB;
    const int cnt = min(EPB, E - base);
    if (tid < NB) { hd[tid] = 0; hs[tid] = 0; }
    __syncthreads();

    int es[16], ed[16];
    #pragma unroll
    for (int i = 0; i < 16; ++i) {
        int g = tid + i * 1024;
        if (g < cnt) { es[i] = src[base + g]; ed[i] = dst[base + g]; }
        else { es[i] = -1; ed[i] = -1; }
    }
    #pragma unroll
    for (int i = 0; i < 16; ++i)
        if (ed[i] >= 0) {
            atomicAdd(&hd[ed[i] >> BSH], 1u);
            atomicAdd(&hs[es[i] >> BSH], 1u);
        }
    __syncthreads();

    // 4 waves: local scans (barrier-free) + global chunk reservation
    {
        const int wv = tid >> 6, lane = tid & 63;
        if (wv == 0) {
            unsigned v[4]; unsigned t = 0;
            #pragma unroll
            for (int j = 0; j < 4; ++j) {
                int i = lane * 4 + j;
                v[j] = (i < NB) ? hd[i] : 0; t += v[j];
            }
            unsigned excl = wave_excl_scan(t, lane);
            #pragma unroll
            for (int j = 0; j < 4; ++j) {
                int i = lane * 4 + j;
                if (i < NB) { ld_[i] = excl; cd[i] = excl; }
                excl += v[j];
            }
        } else if (wv == 1) {
            unsigned v[4]; unsigned t = 0;
            #pragma unroll
            for (int j = 0; j < 4; ++j) {
                int i = lane * 4 + j;
                v[j] = (i < NB) ? hs[i] : 0; t += v[j];
            }
            unsigned excl = wave_excl_scan(t, lane);
            #pragma unroll
            for (int j = 0; j < 4; ++j) {
                int i = lane * 4 + j;
                if (i < NB) { ls_[i] = excl; cs[i] = excl; }
                excl += v[j];
            }
        } else if (wv == 2) {
            for (int i = lane; i < NB; i += 64) bd[i] = atomicAdd(&gcur_d[i * 16], hd[i]);
        } else if (wv == 3) {
            for (int i = lane; i < NB; i += 64) bs[i] = atomicAdd(&gcur_s[i * 16], hs[i]);
        }
    }
    __syncthreads();

    #pragma unroll
    for (int i = 0; i < 16; ++i)
        if (ed[i] >= 0) {
            int b = ed[i] >> BSH;
            unsigned p = atomicAdd(&cd[b], 1u);
            stage_d[p] = ((unsigned)(ed[i] & ((1 << BSH) - 1)) << 17) | (unsigned)es[i];
            sbd[p] = (unsigned char)b;
            int b2 = es[i] >> BSH;
            unsigned p2 = atomicAdd(&cs[b2], 1u);
            stage_s[p2] = (ushort)(es[i] & ((1 << BSH) - 1));
            sbs[p2] = (unsigned char)b2;
        }
    __syncthreads();

    for (int i = tid; i < cnt; i += 1024) {
        unsigned b = sbd[i];
        outd[bd[b] + (unsigned)i - ld_[b]] = stage_d[i];
        unsigned b2 = sbs[i];
        outs[bs[b2] + (unsigned)i - ls_[b2]] = stage_s[i];
    }
}

// ---------------- B: per-bucket finalize. blocks [0,NB): CSR; [NB,2NB): degout+prescale ----------------
__global__ __launch_bounds__(1024)
void k_finalize(const unsigned* __restrict__ outd, const ushort* __restrict__ outs,
                const unsigned* __restrict__ gcur_d, const unsigned* __restrict__ gcur_s,
                int* __restrict__ row_ptr, int* __restrict__ deg_in,
                int* __restrict__ csr_src, float* __restrict__ dni,
                const float* __restrict__ feat, float* __restrict__ dno,
                ushort* __restrict__ Xb) {
    __shared__ unsigned h[512];
    __shared__ unsigned aux[512];
    const int tid = threadIdx.x;
    if (blockIdx.x < NB) {
        // ---- CSR finalize for dst-bucket b ----
        const int b = blockIdx.x;
        const unsigned beg = (unsigned)(b * CAP);
        const int cnt = (int)(gcur_d[b * 16] - beg);
        if (tid < 512) h[tid] = 0;
        __syncthreads();
        for (int i = tid; i < cnt; i += 1024) atomicAdd(&h[outd[beg + i] >> 17], 1u);
        __syncthreads();
        if (tid < 64) {
            const int lane = tid;
            unsigned v[8]; unsigned t = 0;
            #pragma unroll
            for (int j = 0; j < 8; ++j) { v[j] = h[lane * 8 + j]; t += v[j]; }
            unsigned excl = wave_excl_scan(t, lane);
            #pragma unroll
            for (int j = 0; j < 8; ++j) { aux[lane * 8 + j] = excl; excl += v[j]; }
        }
        __syncthreads();
        const int n0 = b << BSH;
        const int nb = min(512, NN - n0);
        if (tid < nb) {
            row_ptr[n0 + tid] = (int)(beg + aux[tid]);
            deg_in[n0 + tid] = (int)h[tid];
            dni[n0 + tid] = rsqrtf(fmaxf((float)h[tid], 1.0f));
        }
        __syncthreads();
        for (int i = tid; i < cnt; i += 1024) {
            unsigned p = outd[beg + i];
            unsigned pos = atomicAdd(&aux[p >> 17], 1u);
            csr_src[beg + pos] = (int)(p & 0x1FFFFu);
        }
    } else {
        // ---- out-degree + feat prescale for src-bucket b ----
        const int b = blockIdx.x - NB;
        const unsigned beg = (unsigned)(b * CAP);
        const int cnt = (int)(gcur_s[b * 16] - beg);
        float* dnl = (float*)aux;
        if (tid < 512) h[tid] = 0;
        __syncthreads();
        for (int i = tid; i < cnt; i += 1024) atomicAdd(&h[outs[beg + i]], 1u);
        __syncthreads();
        const int n0 = b << BSH;
        const int nb = min(512, NN - n0);
        if (tid < nb) {
            float d = rsqrtf(fmaxf((float)h[tid], 1.0f));
            dno[n0 + tid] = d;
            dnl[tid] = d;
        }
        __syncthreads();
        const int total4 = nb * 32;
        for (int slot = tid; slot < total4; slot += 1024) {
            int r = slot >> 5, c4 = slot & 31;
            float s = dnl[r];
            float4 v = reinterpret_cast<const float4*>(feat)[(size_t)(n0 + r) * 32 + c4];
            ushort4 o;
            o.x = f2bf(v.x * s); o.y = f2bf(v.y * s);
            o.z = f2bf(v.z * s); o.w = f2bf(v.w * s);
            reinterpret_cast<ushort4*>(Xb)[(size_t)(n0 + r) * 32 + c4] = o;
        }
    }
}

// ---------------- pull SpMM over bf16 rows (layer 1, F=128) ----------------
__global__ __launch_bounds__(256)
void k_spmm_l1(const int* __restrict__ row_ptr, const int* __restrict__ deg_in,
               const int* __restrict__ csr_src, const ushort* __restrict__ X,
               const float* __restrict__ dni, ushort* __restrict__ Y, int N) {
    const int node = blockIdx.x * 4 + (threadIdx.x >> 6);
    if (node >= N) return;
    const int lane = threadIdx.x & 63;
    const int beg = row_ptr[node];
    const int end = beg + deg_in[node];
    float acc[4] = {0.f, 0.f, 0.f, 0.f};
    const int half = lane >> 5;
    const int l = lane & 31;
    const ushort* Xl = X + l * 4;
    for (int e = beg + half; e < end; e += 2) {
        int s = csr_src[e];
        ushort4 v = *reinterpret_cast<const ushort4*>(Xl + (size_t)s * 128);
        acc[0] += bf2f(v.x); acc[1] += bf2f(v.y);
        acc[2] += bf2f(v.z); acc[3] += bf2f(v.w);
    }
    acc[0] += __shfl_xor(acc[0], 32);
    acc[1] += __shfl_xor(acc[1], 32);
    acc[2] += __shfl_xor(acc[2], 32);
    acc[3] += __shfl_xor(acc[3], 32);
    if (half == 0) {
        float wi = dni[node];
        ushort4 o;
        o.x = f2bf(acc[0] * wi); o.y = f2bf(acc[1] * wi);
        o.z = f2bf(acc[2] * wi); o.w = f2bf(acc[3] * wi);
        *reinterpret_cast<ushort4*>(Y + (size_t)node * 128 + l * 4) = o;
    }
}

// ---------------- fused BN1+ReLU+dno-prescale + pull SpMM (layer 2, F=256) ----------------
__global__ __launch_bounds__(256)
void k_spmm_bn(const int* __restrict__ row_ptr, const int* __restrict__ deg_in,
               const int* __restrict__ csr_src, const ushort* __restrict__ Gb,
               const float* __restrict__ stats, const float* __restrict__ gamma,
               const float* __restrict__ beta, const float* __restrict__ dno,
               const float* __restrict__ dni, ushort* __restrict__ Y, int N) {
    __shared__ float sc_s[HID], sh_s[HID];
    {
        int c = threadIdx.x;
        float inv_n = 1.0f / (float)NN;
        float mean = stats[c] * inv_n;
        float var = stats[HID + c] * inv_n - mean * mean;
        float sc = gamma[c] * rsqrtf(var + BN_EPS);
        sc_s[c] = sc;
        sh_s[c] = beta[c] - mean * sc;
    }
    __syncthreads();
    const int node = blockIdx.x * 4 + (threadIdx.x >> 6);
    if (node >= N) return;
    const int lane = threadIdx.x & 63;
    const int c0 = lane * 4;
    float sc[4], sh[4];
    #pragma unroll
    for (int j = 0; j < 4; ++j) { sc[j] = sc_s[c0 + j]; sh[j] = sh_s[c0 + j]; }
    const int beg = row_ptr[node];
    const int end = beg + deg_in[node];
    float acc[4] = {0.f, 0.f, 0.f, 0.f};
    const ushort* Gl = Gb + c0;
    int e = beg;
    for (; e + 1 < end; e += 2) {
        int s0 = csr_src[e];
        int s1 = csr_src[e + 1];
        float w0 = dno[s0];
        float w1 = dno[s1];
        ushort4 v0 = *reinterpret_cast<const ushort4*>(Gl + (size_t)s0 * 256);
        ushort4 v1 = *reinterpret_cast<const ushort4*>(Gl + (size_t)s1 * 256);
        const ushort* p0 = &v0.x;
        const ushort* p1 = &v1.x;
        #pragma unroll
        for (int j = 0; j < 4; ++j) {
            float y0 = fmaf(bf2f(p0[j]), sc[j], sh[j]);
            y0 = y0 > 0.f ? y0 : 0.f;
            acc[j] = fmaf(y0, w0, acc[j]);
            float y1 = fmaf(bf2f(p1[j]), sc[j], sh[j]);
            y1 = y1 > 0.f ? y1 : 0.f;
            acc[j] = fmaf(y1, w1, acc[j]);
        }
    }
    if (e < end) {
        int s0 = csr_src[e];
        float w0 = dno[s0];
        ushort4 v0 = *reinterpret_cast<const ushort4*>(Gl + (size_t)s0 * 256);
        const ushort* p0 = &v0.x;
        #pragma unroll
        for (int j = 0; j < 4; ++j) {
            float y0 = fmaf(bf2f(p0[j]), sc[j], sh[j]);
            y0 = y0 > 0.f ? y0 : 0.f;
            acc[j] = fmaf(y0, w0, acc[j]);
        }
    }
    float wi = dni[node];
    ushort4 o;
    o.x = f2bf(acc[0] * wi); o.y = f2bf(acc[1] * wi);
    o.z = f2bf(acc[2] * wi); o.w = f2bf(acc[3] * wi);
    *reinterpret_cast<ushort4*>(Y + (size_t)node * 256 + c0) = o;
}

// ---------------- MFMA GEMM 128x256 tile + fused BN column stats ----------------
template <int K>
__global__ __launch_bounds__(256, 2)
void k_gemm_mfma(const ushort* __restrict__ A, const ushort* __restrict__ Wt,
                 const float* __restrict__ bias, ushort* __restrict__ outb,
                 float* __restrict__ stats, int M) {
    __shared__ ushort As[128][40];
    __shared__ ushort Bs[256][40];
    __shared__ float sred[4][2][128];
    const int tid = threadIdx.x;
    const int w = tid >> 6;
    const int lane = tid & 63;
    const int wr = (w >> 1) * 64;
    const int wc = (w & 1) * 128;
    const int row0 = blockIdx.x * 128;
    f32x4 acc[4][8] = {};

    const int frow = lane & 15;
    const int fk = (lane >> 4) * 8;

    for (int k0 = 0; k0 < K; k0 += 32) {
        #pragma unroll
        for (int h = 0; h < 2; ++h) {
            int slot = tid + 256 * h;
            int r = slot >> 2;
            int c = (slot & 3) * 8;
            int row = row0 + r;
            int4 v = make_int4(0, 0, 0, 0);
            if (row < M) v = *reinterpret_cast<const int4*>(A + (size_t)row * K + k0 + c);
            *reinterpret_cast<int4*>(&As[r][c]) = v;
        }
        #pragma unroll
        for (int h = 0; h < 4; ++h) {
            int slot = tid + 256 * h;
            int n = slot >> 2;
            int c = (slot & 3) * 8;
            int4 v = *reinterpret_cast<const int4*>(Wt + (size_t)n * K + k0 + c);
            *reinterpret_cast<int4*>(&Bs[n][c]) = v;
        }
        __syncthreads();

        short8 afr[4], bfr[8];
        #pragma unroll
        for (int mi = 0; mi < 4; ++mi)
            afr[mi] = *reinterpret_cast<const short8*>(&As[wr + mi * 16 + frow][fk]);
        #pragma unroll
        for (int ni = 0; ni < 8; ++ni)
            bfr[ni] = *reinterpret_cast<const short8*>(&Bs[wc + ni * 16 + frow][fk]);
        #pragma unroll
        for (int mi = 0; mi < 4; ++mi)
            #pragma unroll
            for (int ni = 0; ni < 8; ++ni)
                acc[mi][ni] = __builtin_amdgcn_mfma_f32_16x16x32_bf16(afr[mi], bfr[ni], acc[mi][ni], 0, 0, 0);
        __syncthreads();
    }

    const int ncol = lane & 15;
    const int rbase = (lane >> 4) * 4;
    #pragma unroll
    for (int ni = 0; ni < 8; ++ni) {
        int col = wc + ni * 16 + ncol;
        float b = bias[col];
        float s1 = 0.f, s2 = 0.f;
        #pragma unroll
        for (int mi = 0; mi < 4; ++mi) {
            #pragma unroll
            for (int q = 0; q < 4; ++q) {
                int row = row0 + wr + mi * 16 + rbase + q;
                if (row < M) {
                    float val = acc[mi][ni][q] + b;
                    outb[(size_t)row * HID + col] = f2bf(val);
                    s1 += val;
                    s2 += val * val;
                }
            }
        }
        s1 += __shfl_xor(s1, 16); s1 += __shfl_xor(s1, 32);
        s2 += __shfl_xor(s2, 16); s2 += __shfl_xor(s2, 32);
        if ((lane >> 4) == 0) {
            sred[w][0][ni * 16 + ncol] = s1;
            sred[w][1][ni * 16 + ncol] = s2;
        }
    }
    __syncthreads();
    {
        int c = tid;
        int half = c >> 7, cl = c & 127;
        float v0 = sred[half][0][cl] + sred[half + 2][0][cl];
        float v1 = sred[half][1][cl] + sred[half + 2][1][cl];
        atomAdd(&stats[c], v0);
        atomAdd(&stats[HID + c], v1);
    }
}

// ---------------- fused BN2 + ReLU + dueling Q head (MFMA) ----------------
__global__ __launch_bounds__(256)
void k_bn_qhead(const ushort* __restrict__ Gb, const float* __restrict__ stats,
                const float* __restrict__ gamma, const float* __restrict__ beta,
                const ushort* __restrict__ Wh, const float* __restrict__ ba,
                const float* __restrict__ bv, float* __restrict__ out, int M) {
    __shared__ ushort As[128][40];
    __shared__ ushort Bs[80][264];
    __shared__ float sc_s[HID], sh_s[HID];
    const int tid = threadIdx.x;
    const int w = tid >> 6;
    const int lane = tid & 63;
    const int row0 = blockIdx.x * 128;
    const int frow = lane & 15;
    const int fk8 = (lane >> 4) * 8;

    {
        float inv_n = 1.0f / (float)NN;
        float mean = stats[tid] * inv_n;
        float var = stats[HID + tid] * inv_n - mean * mean;
        float sc = gamma[tid] * rsqrtf(var + BN_EPS);
        sc_s[tid] = sc;
        sh_s[tid] = beta[tid] - mean * sc;
    }
    #pragma unroll
    for (int h = 0; h < 10; ++h) {
        int slot = tid + 256 * h;
        int n = slot >> 5;
        int c = (slot & 31) * 8;
        int4 v = *reinterpret_cast<const int4*>(Wh + (size_t)n * HID + c);
        *reinterpret_cast<int4*>(&Bs[n][c]) = v;
    }
    __syncthreads();

    f32x4 acc[2][5] = {};
    for (int k0 = 0; k0 < HID; k0 += 32) {
        #pragma unroll
        for (int h = 0; h < 2; ++h) {
            int slot = tid + 256 * h;
            int r = slot >> 2;
            int c = (slot & 3) * 8;
            int row = row0 + r;
            short8 o = {};
            if (row < M) {
                short8 v = *reinterpret_cast<const short8*>(Gb + (size_t)row * HID + k0 + c);
                #pragma unroll
                for (int j = 0; j < 8; ++j) {
                    int k = k0 + c + j;
                    float y = fmaf(bf2f((ushort)v[j]), sc_s[k], sh_s[k]);
                    o[j] = (short)f2bf(y > 0.f ? y : 0.f);
                }
            }
            *reinterpret_cast<short8*>(&As[r][c]) = o;
        }
        __syncthreads();
        short8 afr[2], bfr[5];
        #pragma unroll
        for (int mi = 0; mi < 2; ++mi)
            afr[mi] = *reinterpret_cast<const short8*>(&As[w * 32 + mi * 16 + frow][fk8]);
        #pragma unroll
        for (int ni = 0; ni < 5; ++ni)
            bfr[ni] = *reinterpret_cast<const short8*>(&Bs[ni * 16 + frow][k0 + fk8]);
        #pragma unroll
        for (int mi = 0; mi < 2; ++mi)
            #pragma unroll
            for (int ni = 0; ni < 5; ++ni)
                acc[mi][ni] = __builtin_amdgcn_mfma_f32_16x16x32_bf16(afr[mi], bfr[ni], acc[mi][ni], 0, 0, 0);
        __syncthreads();
    }

    const int ncol = lane & 15;
    const int gb = lane & 48;
    const float bv0 = bv[0];
    float ba_l[4];
    #pragma unroll
    for (int ni = 0; ni < 4; ++ni) ba_l[ni] = ba[ni * 16 + ncol];
    #pragma unroll
    for (int mi = 0; mi < 2; ++mi) {
        #pragma unroll
        for (int q = 0; q < 4; ++q) {
            int row = row0 + w * 32 + mi * 16 + (lane >> 4) * 4 + q;
            float adv[4];
            float s = 0.f;
            #pragma unroll
            for (int ni = 0; ni < 4; ++ni) {
                adv[ni] = acc[mi][ni][q] + ba_l[ni];
                s += adv[ni];
            }
            s += __shfl_xor(s, 1); s += __shfl_xor(s, 2);
            s += __shfl_xor(s, 4); s += __shfl_xor(s, 8);
            float mean = s * (1.0f / ADIM);
            float val = acc[mi][4][q] + bv0;
            val = __shfl(val, gb);
            if (row < M) {
                #pragma unroll
                for (int ni = 0; ni < 4; ++ni)
                    out[(size_t)row * ADIM + ni * 16 + ncol] = val + adv[ni] - mean;
            }
        }
    }
}

extern "C" void kernel_launch(void* const* d_in, const int* in_sizes, int n_in,
                              void* d_out, int out_size, void* d_ws, size_t ws_size,
                              hipStream_t stream) {
    const float* feat = (const float*)d_in[0];
    const int* src = (const int*)d_in[1];
    const int* dst = (const int*)d_in[2];
    const float* W1 = (const float*)d_in[3];
    const float* b1 = (const float*)d_in[4];
    const float* g1 = (const float*)d_in[5];
    const float* be1 = (const float*)d_in[6];
    const float* W2 = (const float*)d_in[7];
    const float* b2 = (const float*)d_in[8];
    const float* g2 = (const float*)d_in[9];
    const float* be2 = (const float*)d_in[10];
    const float* Wa = (const float*)d_in[11];
    const float* ba = (const float*)d_in[12];
    const float* Wv = (const float*)d_in[13];
    const float* bv = (const float*)d_in[14];
    float* out = (float*)d_out;

    char* w = (char*)d_ws;
    float* stats     = (float*)w;     w += 1024 * 4;
    unsigned* gcur_d = (unsigned*)w;  w += (size_t)NB * 16 * 4;
    unsigned* gcur_s = (unsigned*)w;  w += (size_t)NB * 16 * 4;
    float* dn_out    = (float*)w;     w += (size_t)NN * 4;
    float* dn_in     = (float*)w;     w += (size_t)NN * 4;
    int* row_ptr     = (int*)w;       w += (size_t)(NN + 4) * 4;
    int* deg_in      = (int*)w;       w += (size_t)(NN + 4) * 4;
    unsigned* outd   = (unsigned*)w;  w += (size_t)NB * CAP * 4;
    ushort* outs     = (ushort*)w;    w += (size_t)NB * CAP * 2;
    int* csr_src     = (int*)w;       w += (size_t)NB * CAP * 4;
    ushort* Wt1      = (ushort*)w;    w += (size_t)HID * SDIM * 2;
    ushort* Wt2      = (ushort*)w;    w += (size_t)HID * HID * 2;
    ushort* Whb      = (ushort*)w;    w += (size_t)80 * HID * 2;
    ushort* Xb       = (ushort*)w;    w += (size_t)NN * SDIM * 2;
    ushort* Ab       = (ushort*)w;    w += (size_t)NN * HID * 2;
    ushort* Gb       = (ushort*)w;    w += (size_t)NN * HID * 2;

    // setup: cursors + stats zero; weight conversion
    k_init<<<1, 256, 0, stream>>>(gcur_d, gcur_s, stats);
    {
        int total = HID * SDIM + HID * HID + 80 * HID;
        k_wprep<<<(total + 255) / 256, 256, 0, stream>>>(W1, W2, Wa, Wv, Wt1, Wt2, Whb);
    }

    // single-pass bucket partition + finalize
    k_part<<<NAB, 1024, 0, stream>>>(src, dst, gcur_d, gcur_s, outd, outs, NE);
    k_finalize<<<2 * NB, 1024, 0, stream>>>(outd, outs, gcur_d, gcur_s, row_ptr, deg_in,
                                            csr_src, dn_in, feat, dn_out, Xb);

    const int gblocks = (NN + 127) / 128;

    // layer 1
    k_spmm_l1<<<(NN + 3) / 4, 256, 0, stream>>>(row_ptr, deg_in, csr_src, Xb, dn_in, Ab, NN);
    k_gemm_mfma<SDIM><<<gblocks, 256, 0, stream>>>(Ab, Wt1, b1, Gb, stats, NN);

    // layer 2
    k_spmm_bn<<<(NN + 3) / 4, 256, 0, stream>>>(row_ptr, deg_in, csr_src, Gb, stats, g1, be1,
                                                dn_out, dn_in, Ab, NN);
    k_gemm_mfma<HID><<<gblocks, 256, 0, stream>>>(Ab, Wt2, b2, Gb, stats + 512, NN);
    k_bn_qhead<<<gblocks, 256, 0, stream>>>(Gb, stats + 512, g2, be2, Whb, ba, bv, out, NN);
}

// Round 10
// 697.486 us; speedup vs baseline: 1.0748x; 1.0052x over previous
//
#include <hip/hip_runtime.h>
#include <hip/hip_bf16.h>

#define NN 100000
#define NE 3200000
#define HID 256
#define SDIM 128
#define ADIM 64
#define BN_EPS 1e-5f

#define BSH 9                       // 512 nodes per bucket
#define NB 196                      // ceil(NN/512)
#define EPB 8192                    // edges per partition block (70 KB LDS -> 2 blocks/CU)
#define NAB 391                     // ceil(NE/EPB)
#define CAP 20480                   // fixed per-bucket capacity (mean 16384, sigma ~128)

typedef __attribute__((ext_vector_type(8))) short short8;
typedef __attribute__((ext_vector_type(4))) float f32x4;

__device__ __forceinline__ void atomAdd(float* p, float v) { unsafeAtomicAdd(p, v); }
__device__ __forceinline__ float bf2f(ushort u) {
    union { unsigned i; float f; } c; c.i = ((unsigned)u) << 16; return c.f;
}
__device__ __forceinline__ ushort f2bf(float x) {
    __hip_bfloat16 h = __float2bfloat16(x);
    return *reinterpret_cast<ushort*>(&h);
}

// wave-exclusive scan helper
__device__ __forceinline__ unsigned wave_excl_scan(unsigned t, int lane) {
    unsigned p = t;
    #pragma unroll
    for (int d = 1; d < 64; d <<= 1) {
        unsigned q = __shfl_up(p, d);
        if (lane >= d) p += q;
    }
    return p - t;
}

// ---------------- setup: block 0 = cursors+stats init; blocks 1.. = weight prep ----------------
__global__ __launch_bounds__(256)
void k_setup(const float* __restrict__ W1, const float* __restrict__ W2,
             const float* __restrict__ Wa, const float* __restrict__ Wv,
             ushort* __restrict__ Wt1, ushort* __restrict__ Wt2, ushort* __restrict__ Wh,
             unsigned* __restrict__ gcur_d, unsigned* __restrict__ gcur_s,
             float* __restrict__ stats) {
    int t = threadIdx.x;
    if (blockIdx.x == 0) {
        if (t < NB) {
            gcur_d[t * 16] = (unsigned)(t * CAP);
            gcur_s[t * 16] = (unsigned)(t * CAP);
        }
        #pragma unroll
        for (int j = 0; j < 4; ++j) stats[t + 256 * j] = 0.f;
        return;
    }
    int idx = (blockIdx.x - 1) * 256 + t;
    if (idx < HID * SDIM) {
        int n = idx / SDIM, k = idx - n * SDIM;
        Wt1[idx] = f2bf(W1[(size_t)k * HID + n]);
    } else if (idx < HID * SDIM + HID * HID) {
        int j = idx - HID * SDIM;
        int n = j / HID, k = j - n * HID;
        Wt2[j] = f2bf(W2[(size_t)k * HID + n]);
    } else if (idx < HID * SDIM + HID * HID + 80 * HID) {
        int j = idx - HID * SDIM - HID * HID;
        int n = j / HID, k = j - n * HID;
        float v = 0.f;
        if (n < ADIM) v = Wa[(size_t)k * ADIM + n];
        else if (n == ADIM) v = Wv[k];
        Wh[j] = f2bf(v);
    }
}

// ---------------- A: partition edges into fixed-capacity buckets (single pass) ----------------
__global__ __launch_bounds__(1024)
void k_part(const int* __restrict__ src, const int* __restrict__ dst,
            unsigned* __restrict__ gcur_d, unsigned* __restrict__ gcur_s,
            unsigned* __restrict__ outd, ushort* __restrict__ outs, int E) {
    __shared__ unsigned hd[NB], hs[NB], ld_[NB], ls_[NB], cd[NB], cs[NB], bd[NB], bs[NB];
    __shared__ unsigned stage_d[EPB];
    __shared__ ushort stage_s[EPB];
    __shared__ unsigned char sbd[EPB], sbs[EPB];
    const int tid = threadIdx.x;
    const int base = blockIdx.x * EPB;
    const int cnt = min(EPB, E - base);
    if (tid < NB) { hd[tid] = 0; hs[tid] = 0; }
    __syncthreads();

    int es[8], ed[8];
    #pragma unroll
    for (int i = 0; i < 8; ++i) {
        int g = tid + i * 1024;
        if (g < cnt) { es[i] = src[base + g]; ed[i] = dst[base + g]; }
        else { es[i] = -1; ed[i] = -1; }
    }
    #pragma unroll
    for (int i = 0; i < 8; ++i)
        if (ed[i] >= 0) {
            atomicAdd(&hd[ed[i] >> BSH], 1u);
            atomicAdd(&hs[es[i] >> BSH], 1u);
        }
    __syncthreads();

    // 4 waves: local scans (barrier-free) + global chunk reservation
    {
        const int wv = tid >> 6, lane = tid & 63;
        if (wv == 0) {
            unsigned v[4]; unsigned t = 0;
            #pragma unroll
            for (int j = 0; j < 4; ++j) {
                int i = lane * 4 + j;
                v[j] = (i < NB) ? hd[i] : 0; t += v[j];
            }
            unsigned excl = wave_excl_scan(t, lane);
            #pragma unroll
            for (int j = 0; j < 4; ++j) {
                int i = lane * 4 + j;
                if (i < NB) { ld_[i] = excl; cd[i] = excl; }
                excl += v[j];
            }
        } else if (wv == 1) {
            unsigned v[4]; unsigned t = 0;
            #pragma unroll
            for (int j = 0; j < 4; ++j) {
                int i = lane * 4 + j;
                v[j] = (i < NB) ? hs[i] : 0; t += v[j];
            }
            unsigned excl = wave_excl_scan(t, lane);
            #pragma unroll
            for (int j = 0; j < 4; ++j) {
                int i = lane * 4 + j;
                if (i < NB) { ls_[i] = excl; cs[i] = excl; }
                excl += v[j];
            }
        } else if (wv == 2) {
            for (int i = lane; i < NB; i += 64) bd[i] = atomicAdd(&gcur_d[i * 16], hd[i]);
        } else if (wv == 3) {
            for (int i = lane; i < NB; i += 64) bs[i] = atomicAdd(&gcur_s[i * 16], hs[i]);
        }
    }
    __syncthreads();

    #pragma unroll
    for (int i = 0; i < 8; ++i)
        if (ed[i] >= 0) {
            int b = ed[i] >> BSH;
            unsigned p = atomicAdd(&cd[b], 1u);
            stage_d[p] = ((unsigned)(ed[i] & ((1 << BSH) - 1)) << 17) | (unsigned)es[i];
            sbd[p] = (unsigned char)b;
            int b2 = es[i] >> BSH;
            unsigned p2 = atomicAdd(&cs[b2], 1u);
            stage_s[p2] = (ushort)(es[i] & ((1 << BSH) - 1));
            sbs[p2] = (unsigned char)b2;
        }
    __syncthreads();

    for (int i = tid; i < cnt; i += 1024) {
        unsigned b = sbd[i];
        outd[bd[b] + (unsigned)i - ld_[b]] = stage_d[i];
        unsigned b2 = sbs[i];
        outs[bs[b2] + (unsigned)i - ls_[b2]] = stage_s[i];
    }
}

// ---------------- B: per-bucket finalize. blocks [0,NB): CSR; [NB,2NB): degout+prescale ----------------
__global__ __launch_bounds__(1024)
void k_finalize(const unsigned* __restrict__ outd, const ushort* __restrict__ outs,
                const unsigned* __restrict__ gcur_d, const unsigned* __restrict__ gcur_s,
                int* __restrict__ row_ptr, int* __restrict__ deg_in,
                int* __restrict__ csr_src, float* __restrict__ dni,
                const float* __restrict__ feat, float* __restrict__ dno,
                ushort* __restrict__ Xb) {
    __shared__ unsigned h[512], h2[512];
    __shared__ unsigned aux[512];
    const int tid = threadIdx.x;
    unsigned* myh = (tid < 512) ? h : h2;  // waves 0-7 vs 8-15
    if (blockIdx.x < NB) {
        // ---- CSR finalize for dst-bucket b ----
        const int b = blockIdx.x;
        const unsigned beg = (unsigned)(b * CAP);
        const int cnt = (int)(gcur_d[b * 16] - beg);
        if (tid < 512) { h[tid] = 0; h2[tid] = 0; }
        __syncthreads();
        for (int i = tid; i < cnt; i += 1024) atomicAdd(&myh[outd[beg + i] >> 17], 1u);
        __syncthreads();
        if (tid < 512) h[tid] += h2[tid];
        __syncthreads();
        if (tid < 64) {
            const int lane = tid;
            unsigned v[8]; unsigned t = 0;
            #pragma unroll
            for (int j = 0; j < 8; ++j) { v[j] = h[lane * 8 + j]; t += v[j]; }
            unsigned excl = wave_excl_scan(t, lane);
            #pragma unroll
            for (int j = 0; j < 8; ++j) { aux[lane * 8 + j] = excl; excl += v[j]; }
        }
        __syncthreads();
        const int n0 = b << BSH;
        const int nb = min(512, NN - n0);
        if (tid < nb) {
            row_ptr[n0 + tid] = (int)(beg + aux[tid]);
            deg_in[n0 + tid] = (int)h[tid];
            dni[n0 + tid] = rsqrtf(fmaxf((float)h[tid], 1.0f));
        }
        __syncthreads();
        for (int i = tid; i < cnt; i += 1024) {
            unsigned p = outd[beg + i];
            unsigned pos = atomicAdd(&aux[p >> 17], 1u);
            csr_src[beg + pos] = (int)(p & 0x1FFFFu);
        }
    } else {
        // ---- out-degree + feat prescale for src-bucket b ----
        const int b = blockIdx.x - NB;
        const unsigned beg = (unsigned)(b * CAP);
        const int cnt = (int)(gcur_s[b * 16] - beg);
        float* dnl = (float*)aux;
        if (tid < 512) { h[tid] = 0; h2[tid] = 0; }
        __syncthreads();
        for (int i = tid; i < cnt; i += 1024) atomicAdd(&myh[outs[beg + i]], 1u);
        __syncthreads();
        if (tid < 512) h[tid] += h2[tid];
        __syncthreads();
        const int n0 = b << BSH;
        const int nb = min(512, NN - n0);
        if (tid < nb) {
            float d = rsqrtf(fmaxf((float)h[tid], 1.0f));
            dno[n0 + tid] = d;
            dnl[tid] = d;
        }
        __syncthreads();
        const int total4 = nb * 32;
        for (int slot = tid; slot < total4; slot += 1024) {
            int r = slot >> 5, c4 = slot & 31;
            float s = dnl[r];
            float4 v = reinterpret_cast<const float4*>(feat)[(size_t)(n0 + r) * 32 + c4];
            ushort4 o;
            o.x = f2bf(v.x * s); o.y = f2bf(v.y * s);
            o.z = f2bf(v.z * s); o.w = f2bf(v.w * s);
            reinterpret_cast<ushort4*>(Xb)[(size_t)(n0 + r) * 32 + c4] = o;
        }
    }
}

// ---------------- pull SpMM over bf16 rows (layer 1, F=128) ----------------
__global__ __launch_bounds__(256)
void k_spmm_l1(const int* __restrict__ row_ptr, const int* __restrict__ deg_in,
               const int* __restrict__ csr_src, const ushort* __restrict__ X,
               const float* __restrict__ dni, ushort* __restrict__ Y, int N) {
    const int node = blockIdx.x * 4 + (threadIdx.x >> 6);
    if (node >= N) return;
    const int lane = threadIdx.x & 63;
    const int beg = row_ptr[node];
    const int end = beg + deg_in[node];
    float acc[4] = {0.f, 0.f, 0.f, 0.f};
    const int half = lane >> 5;
    const int l = lane & 31;
    const ushort* Xl = X + l * 4;
    for (int e = beg + half; e < end; e += 2) {
        int s = csr_src[e];
        ushort4 v = *reinterpret_cast<const ushort4*>(Xl + (size_t)s * 128);
        acc[0] += bf2f(v.x); acc[1] += bf2f(v.y);
        acc[2] += bf2f(v.z); acc[3] += bf2f(v.w);
    }
    acc[0] += __shfl_xor(acc[0], 32);
    acc[1] += __shfl_xor(acc[1], 32);
    acc[2] += __shfl_xor(acc[2], 32);
    acc[3] += __shfl_xor(acc[3], 32);
    if (half == 0) {
        float wi = dni[node];
        ushort4 o;
        o.x = f2bf(acc[0] * wi); o.y = f2bf(acc[1] * wi);
        o.z = f2bf(acc[2] * wi); o.w = f2bf(acc[3] * wi);
        *reinterpret_cast<ushort4*>(Y + (size_t)node * 128 + l * 4) = o;
    }
}

// ---------------- fused BN1+ReLU+dno-prescale + pull SpMM (layer 2, F=256) ----------------
__global__ __launch_bounds__(256)
void k_spmm_bn(const int* __restrict__ row_ptr, const int* __restrict__ deg_in,
               const int* __restrict__ csr_src, const ushort* __restrict__ Gb,
               const float* __restrict__ stats, const float* __restrict__ gamma,
               const float* __restrict__ beta, const float* __restrict__ dno,
               const float* __restrict__ dni, ushort* __restrict__ Y, int N) {
    __shared__ float sc_s[HID], sh_s[HID];
    {
        int c = threadIdx.x;
        float inv_n = 1.0f / (float)NN;
        float mean = stats[c] * inv_n;
        float var = stats[HID + c] * inv_n - mean * mean;
        float sc = gamma[c] * rsqrtf(var + BN_EPS);
        sc_s[c] = sc;
        sh_s[c] = beta[c] - mean * sc;
    }
    __syncthreads();
    const int node = blockIdx.x * 4 + (threadIdx.x >> 6);
    if (node >= N) return;
    const int lane = threadIdx.x & 63;
    const int c0 = lane * 4;
    float sc[4], sh[4];
    #pragma unroll
    for (int j = 0; j < 4; ++j) { sc[j] = sc_s[c0 + j]; sh[j] = sh_s[c0 + j]; }
    const int beg = row_ptr[node];
    const int end = beg + deg_in[node];
    float acc[4] = {0.f, 0.f, 0.f, 0.f};
    const ushort* Gl = Gb + c0;
    int e = beg;
    for (; e + 1 < end; e += 2) {
        int s0 = csr_src[e];
        int s1 = csr_src[e + 1];
        float w0 = dno[s0];
        float w1 = dno[s1];
        ushort4 v0 = *reinterpret_cast<const ushort4*>(Gl + (size_t)s0 * 256);
        ushort4 v1 = *reinterpret_cast<const ushort4*>(Gl + (size_t)s1 * 256);
        const ushort* p0 = &v0.x;
        const ushort* p1 = &v1.x;
        #pragma unroll
        for (int j = 0; j < 4; ++j) {
            float y0 = fmaf(bf2f(p0[j]), sc[j], sh[j]);
            y0 = y0 > 0.f ? y0 : 0.f;
            acc[j] = fmaf(y0, w0, acc[j]);
            float y1 = fmaf(bf2f(p1[j]), sc[j], sh[j]);
            y1 = y1 > 0.f ? y1 : 0.f;
            acc[j] = fmaf(y1, w1, acc[j]);
        }
    }
    if (e < end) {
        int s0 = csr_src[e];
        float w0 = dno[s0];
        ushort4 v0 = *reinterpret_cast<const ushort4*>(Gl + (size_t)s0 * 256);
        const ushort* p0 = &v0.x;
        #pragma unroll
        for (int j = 0; j < 4; ++j) {
            float y0 = fmaf(bf2f(p0[j]), sc[j], sh[j]);
            y0 = y0 > 0.f ? y0 : 0.f;
            acc[j] = fmaf(y0, w0, acc[j]);
        }
    }
    float wi = dni[node];
    ushort4 o;
    o.x = f2bf(acc[0] * wi); o.y = f2bf(acc[1] * wi);
    o.z = f2bf(acc[2] * wi); o.w = f2bf(acc[3] * wi);
    *reinterpret_cast<ushort4*>(Y + (size_t)node * 256 + c0) = o;
}

// ---------------- MFMA GEMM 128x256 tile + fused BN column stats ----------------
template <int K>
__global__ __launch_bounds__(256, 2)
void k_gemm_mfma(const ushort* __restrict__ A, const ushort* __restrict__ Wt,
                 const float* __restrict__ bias, ushort* __restrict__ outb,
                 float* __restrict__ stats, int M) {
    __shared__ ushort As[128][40];
    __shared__ ushort Bs[256][40];
    __shared__ float sred[4][2][128];
    const int tid = threadIdx.x;
    const int w = tid >> 6;
    const int lane = tid & 63;
    const int wr = (w >> 1) * 64;
    const int wc = (w & 1) * 128;
    const int row0 = blockIdx.x * 128;
    f32x4 acc[4][8] = {};

    const int frow = lane & 15;
    const int fk = (lane >> 4) * 8;

    for (int k0 = 0; k0 < K; k0 += 32) {
        #pragma unroll
        for (int h = 0; h < 2; ++h) {
            int slot = tid + 256 * h;
            int r = slot >> 2;
            int c = (slot & 3) * 8;
            int row = row0 + r;
            int4 v = make_int4(0, 0, 0, 0);
            if (row < M) v = *reinterpret_cast<const int4*>(A + (size_t)row * K + k0 + c);
            *reinterpret_cast<int4*>(&As[r][c]) = v;
        }
        #pragma unroll
        for (int h = 0; h < 4; ++h) {
            int slot = tid + 256 * h;
            int n = slot >> 2;
            int c = (slot & 3) * 8;
            int4 v = *reinterpret_cast<const int4*>(Wt + (size_t)n * K + k0 + c);
            *reinterpret_cast<int4*>(&Bs[n][c]) = v;
        }
        __syncthreads();

        short8 afr[4], bfr[8];
        #pragma unroll
        for (int mi = 0; mi < 4; ++mi)
            afr[mi] = *reinterpret_cast<const short8*>(&As[wr + mi * 16 + frow][fk]);
        #pragma unroll
        for (int ni = 0; ni < 8; ++ni)
            bfr[ni] = *reinterpret_cast<const short8*>(&Bs[wc + ni * 16 + frow][fk]);
        #pragma unroll
        for (int mi = 0; mi < 4; ++mi)
            #pragma unroll
            for (int ni = 0; ni < 8; ++ni)
                acc[mi][ni] = __builtin_amdgcn_mfma_f32_16x16x32_bf16(afr[mi], bfr[ni], acc[mi][ni], 0, 0, 0);
        __syncthreads();
    }

    const int ncol = lane & 15;
    const int rbase = (lane >> 4) * 4;
    #pragma unroll
    for (int ni = 0; ni < 8; ++ni) {
        int col = wc + ni * 16 + ncol;
        float b = bias[col];
        float s1 = 0.f, s2 = 0.f;
        #pragma unroll
        for (int mi = 0; mi < 4; ++mi) {
            #pragma unroll
            for (int q = 0; q < 4; ++q) {
                int row = row0 + wr + mi * 16 + rbase + q;
                if (row < M) {
                    float val = acc[mi][ni][q] + b;
                    outb[(size_t)row * HID + col] = f2bf(val);
                    s1 += val;
                    s2 += val * val;
                }
            }
        }
        s1 += __shfl_xor(s1, 16); s1 += __shfl_xor(s1, 32);
        s2 += __shfl_xor(s2, 16); s2 += __shfl_xor(s2, 32);
        if ((lane >> 4) == 0) {
            sred[w][0][ni * 16 + ncol] = s1;
            sred[w][1][ni * 16 + ncol] = s2;
        }
    }
    __syncthreads();
    {
        int c = tid;
        int half = c >> 7, cl = c & 127;
        float v0 = sred[half][0][cl] + sred[half + 2][0][cl];
        float v1 = sred[half][1][cl] + sred[half + 2][1][cl];
        atomAdd(&stats[c], v0);
        atomAdd(&stats[HID + c], v1);
    }
}

// ---------------- fused BN2 + ReLU + dueling Q head (MFMA) ----------------
__global__ __launch_bounds__(256)
void k_bn_qhead(const ushort* __restrict__ Gb, const float* __restrict__ stats,
                const float* __restrict__ gamma, const float* __restrict__ beta,
                const ushort* __restrict__ Wh, const float* __restrict__ ba,
                const float* __restrict__ bv, float* __restrict__ out, int M) {
    __shared__ ushort As[128][40];
    __shared__ ushort Bs[80][264];
    __shared__ float sc_s[HID], sh_s[HID];
    const int tid = threadIdx.x;
    const int w = tid >> 6;
    const int lane = tid & 63;
    const int row0 = blockIdx.x * 128;
    const int frow = lane & 15;
    const int fk8 = (lane >> 4) * 8;

    {
        float inv_n = 1.0f / (float)NN;
        float mean = stats[tid] * inv_n;
        float var = stats[HID + tid] * inv_n - mean * mean;
        float sc = gamma[tid] * rsqrtf(var + BN_EPS);
        sc_s[tid] = sc;
        sh_s[tid] = beta[tid] - mean * sc;
    }
    #pragma unroll
    for (int h = 0; h < 10; ++h) {
        int slot = tid + 256 * h;
        int n = slot >> 5;
        int c = (slot & 31) * 8;
        int4 v = *reinterpret_cast<const int4*>(Wh + (size_t)n * HID + c);
        *reinterpret_cast<int4*>(&Bs[n][c]) = v;
    }
    __syncthreads();

    f32x4 acc[2][5] = {};
    for (int k0 = 0; k0 < HID; k0 += 32) {
        #pragma unroll
        for (int h = 0; h < 2; ++h) {
            int slot = tid + 256 * h;
            int r = slot >> 2;
            int c = (slot & 3) * 8;
            int row = row0 + r;
            short8 o = {};
            if (row < M) {
                short8 v = *reinterpret_cast<const short8*>(Gb + (size_t)row * HID + k0 + c);
                #pragma unroll
                for (int j = 0; j < 8; ++j) {
                    int k = k0 + c + j;
                    float y = fmaf(bf2f((ushort)v[j]), sc_s[k], sh_s[k]);
                    o[j] = (short)f2bf(y > 0.f ? y : 0.f);
                }
            }
            *reinterpret_cast<short8*>(&As[r][c]) = o;
        }
        __syncthreads();
        short8 afr[2], bfr[5];
        #pragma unroll
        for (int mi = 0; mi < 2; ++mi)
            afr[mi] = *reinterpret_cast<const short8*>(&As[w * 32 + mi * 16 + frow][fk8]);
        #pragma unroll
        for (int ni = 0; ni < 5; ++ni)
            bfr[ni] = *reinterpret_cast<const short8*>(&Bs[ni * 16 + frow][k0 + fk8]);
        #pragma unroll
        for (int mi = 0; mi < 2; ++mi)
            #pragma unroll
            for (int ni = 0; ni < 5; ++ni)
                acc[mi][ni] = __builtin_amdgcn_mfma_f32_16x16x32_bf16(afr[mi], bfr[ni], acc[mi][ni], 0, 0, 0);
        __syncthreads();
    }

    const int ncol = lane & 15;
    const int gb = lane & 48;
    const float bv0 = bv[0];
    float ba_l[4];
    #pragma unroll
    for (int ni = 0; ni < 4; ++ni) ba_l[ni] = ba[ni * 16 + ncol];
    #pragma unroll
    for (int mi = 0; mi < 2; ++mi) {
        #pragma unroll
        for (int q = 0; q < 4; ++q) {
            int row = row0 + w * 32 + mi * 16 + (lane >> 4) * 4 + q;
            float adv[4];
            float s = 0.f;
            #pragma unroll
            for (int ni = 0; ni < 4; ++ni) {
                adv[ni] = acc[mi][ni][q] + ba_l[ni];
                s += adv[ni];
            }
            s += __shfl_xor(s, 1); s += __shfl_xor(s, 2);
            s += __shfl_xor(s, 4); s += __shfl_xor(s, 8);
            float mean = s * (1.0f / ADIM);
            float val = acc[mi][4][q] + bv0;
            val = __shfl(val, gb);
            if (row < M) {
                #pragma unroll
                for (int ni = 0; ni < 4; ++ni)
                    out[(size_t)row * ADIM + ni * 16 + ncol] = val + adv[ni] - mean;
            }
        }
    }
}

extern "C" void kernel_launch(void* const* d_in, const int* in_sizes, int n_in,
                              void* d_out, int out_size, void* d_ws, size_t ws_size,
                              hipStream_t stream) {
    const float* feat = (const float*)d_in[0];
    const int* src = (const int*)d_in[1];
    const int* dst = (const int*)d_in[2];
    const float* W1 = (const float*)d_in[3];
    const float* b1 = (const float*)d_in[4];
    const float* g1 = (const float*)d_in[5];
    const float* be1 = (const float*)d_in[6];
    const float* W2 = (const float*)d_in[7];
    const float* b2 = (const float*)d_in[8];
    const float* g2 = (const float*)d_in[9];
    const float* be2 = (const float*)d_in[10];
    const float* Wa = (const float*)d_in[11];
    const float* ba = (const float*)d_in[12];
    const float* Wv = (const float*)d_in[13];
    const float* bv = (const float*)d_in[14];
    float* out = (float*)d_out;

    char* w = (char*)d_ws;
    float* stats     = (float*)w;     w += 1024 * 4;
    unsigned* gcur_d = (unsigned*)w;  w += (size_t)NB * 16 * 4;
    unsigned* gcur_s = (unsigned*)w;  w += (size_t)NB * 16 * 4;
    float* dn_out    = (float*)w;     w += (size_t)NN * 4;
    float* dn_in     = (float*)w;     w += (size_t)NN * 4;
    int* row_ptr     = (int*)w;       w += (size_t)(NN + 4) * 4;
    int* deg_in      = (int*)w;       w += (size_t)(NN + 4) * 4;
    unsigned* outd   = (unsigned*)w;  w += (size_t)NB * CAP * 4;
    ushort* outs     = (ushort*)w;    w += (size_t)NB * CAP * 2;
    int* csr_src     = (int*)w;       w += (size_t)NB * CAP * 4;
    ushort* Wt1      = (ushort*)w;    w += (size_t)HID * SDIM * 2;
    ushort* Wt2      = (ushort*)w;    w += (size_t)HID * HID * 2;
    ushort* Whb      = (ushort*)w;    w += (size_t)80 * HID * 2;
    ushort* Xb       = (ushort*)w;    w += (size_t)NN * SDIM * 2;
    ushort* Ab       = (ushort*)w;    w += (size_t)NN * HID * 2;
    ushort* Gb       = (ushort*)w;    w += (size_t)NN * HID * 2;

    // setup: block 0 = cursor/stats init, rest = weight conversion
    {
        int total = HID * SDIM + HID * HID + 80 * HID;
        k_setup<<<1 + (total + 255) / 256, 256, 0, stream>>>(W1, W2, Wa, Wv, Wt1, Wt2, Whb,
                                                             gcur_d, gcur_s, stats);
    }

    // single-pass bucket partition + finalize
    k_part<<<NAB, 1024, 0, stream>>>(src, dst, gcur_d, gcur_s, outd, outs, NE);
    k_finalize<<<2 * NB, 1024, 0, stream>>>(outd, outs, gcur_d, gcur_s, row_ptr, deg_in,
                                            csr_src, dn_in, feat, dn_out, Xb);

    const int gblocks = (NN + 127) / 128;

    // layer 1
    k_spmm_l1<<<(NN + 3) / 4, 256, 0, stream>>>(row_ptr, deg_in, csr_src, Xb, dn_in, Ab, NN);
    k_gemm_mfma<SDIM><<<gblocks, 256, 0, stream>>>(Ab, Wt1, b1, Gb, stats, NN);

    // layer 2
    k_spmm_bn<<<(NN + 3) / 4, 256, 0, stream>>>(row_ptr, deg_in, csr_src, Gb, stats, g1, be1,
                                                dn_out, dn_in, Ab, NN);
    k_gemm_mfma<HID><<<gblocks, 256, 0, stream>>>(Ab, Wt2, b2, Gb, stats + 512, NN);
    k_bn_qhead<<<gblocks, 256, 0, stream>>>(Gb, stats + 512, g2, be2, Whb, ba, bv, out, NN);
}